// Round 7
// baseline (644.317 us; speedup 1.0000x reference)
//
#include <hip/hip_runtime.h>

typedef unsigned short u16;
using bf16x8 = __attribute__((ext_vector_type(8))) short;
using f32x4  = __attribute__((ext_vector_type(4))) float;

#define CH   1024
#define NP   2048
#define CQ   128

__device__ __forceinline__ float bf2f(u16 u){
  union { unsigned u; float f; } c; c.u = ((unsigned)u) << 16; return c.f;
}
__device__ __forceinline__ u16 f2bf(float f){
  unsigned x = __float_as_uint(f);
  unsigned r = (x + 0x7fffu + ((x >> 16) & 1u)) >> 16;
  return (u16)r;
}

__device__ __forceinline__ void gl2lds16(const u16* g, u16* l){
  __builtin_amdgcn_global_load_lds(
      (const __attribute__((address_space(1))) unsigned int*)(const void*)g,
      (__attribute__((address_space(3))) unsigned int*)(void*)l,
      16, 0, 0);
}

__global__ void ws_marker(float* out, float have_mb){
  out[0] = 1048576.0f + have_mb;
}

// ---------------------------------------------------------------------------
// Transpose+split: x [b][c][n] fp32 -> xh,xl [b][n][c] bf16 (hi/lo split)
// ---------------------------------------------------------------------------
__global__ __launch_bounds__(256) void transpose_split(const float* __restrict__ x,
                                                       u16* __restrict__ xh,
                                                       u16* __restrict__ xl){
  const int bb = blockIdx.z;
  const int n0 = blockIdx.x * 64, c0 = blockIdx.y * 64;
  __shared__ float tile[64][65];
  const int t = threadIdx.x;
  const float* xb = x + ((size_t)bb*CH + c0)*NP + n0;
#pragma unroll
  for (int rr = 0; rr < 4; ++rr){
    const int c_l = (t >> 4) + rr*16;
    const int n_l = (t & 15) * 4;
    float4 v = *(const float4*)&xb[(size_t)c_l*NP + n_l];
    tile[c_l][n_l+0] = v.x; tile[c_l][n_l+1] = v.y;
    tile[c_l][n_l+2] = v.z; tile[c_l][n_l+3] = v.w;
  }
  __syncthreads();
  u16* oh = xh + ((size_t)bb*NP + n0)*CH + c0;
  u16* ol = xl + ((size_t)bb*NP + n0)*CH + c0;
#pragma unroll
  for (int rr = 0; rr < 4; ++rr){
    const int n_l = (t >> 4) + rr*16;
    const int c_l = (t & 15) * 4;
    ushort4 h, l;
    float v0 = tile[c_l+0][n_l], v1 = tile[c_l+1][n_l];
    float v2 = tile[c_l+2][n_l], v3 = tile[c_l+3][n_l];
    h.x = f2bf(v0); l.x = f2bf(v0 - bf2f(h.x));
    h.y = f2bf(v1); l.y = f2bf(v1 - bf2f(h.y));
    h.z = f2bf(v2); l.z = f2bf(v2 - bf2f(h.z));
    h.w = f2bf(v3); l.w = f2bf(v3 - bf2f(h.w));
    *(ushort4*)&oh[(size_t)n_l*CH + c_l] = h;
    *(ushort4*)&ol[(size_t)n_l*CH + c_l] = l;
  }
}

// ---------------------------------------------------------------------------
// Prep: weight splits (w3/w4 stacked), BN-param concat, colsum zero.
// ---------------------------------------------------------------------------
__global__ __launch_bounds__(256) void prep_all(
    const float* __restrict__ w0, const float* __restrict__ w1,
    const float* __restrict__ w2, const float* __restrict__ w3,
    const float* __restrict__ w4,
    u16* w1h, u16* w1l, u16* w2h,
    u16* w34h, u16* w34l, u16* w5h,
    const float* g3, const float* b3, const float* m3, const float* v3,
    const float* g4, const float* b4, const float* m4, const float* v4,
    float* p34, float* colsum){
  const int seg = blockIdx.y;
  if (seg == 5){
    for (int i = blockIdx.x*blockDim.x + threadIdx.x; i < 1024; i += gridDim.x*blockDim.x){
      const int grp = i >> 8, j = i & 255;
      const float* pa = (grp==0) ? g3 : (grp==1) ? b3 : (grp==2) ? m3 : v3;
      const float* pb = (grp==0) ? g4 : (grp==1) ? b4 : (grp==2) ? m4 : v4;
      p34[i] = (j < 128) ? pa[j] : pb[j-128];
    }
    return;
  }
  if (seg == 6){
    for (int i = blockIdx.x*blockDim.x + threadIdx.x; i < 8*NP; i += gridDim.x*blockDim.x)
      colsum[i] = 0.f;
    return;
  }
  const float* w; u16 *wh, *wl; int n;
  switch (seg){
    case 0:  w = w0; wh = w1h;           wl = w1l;           n = CH*CH; break;
    case 1:  w = w1; wh = w2h;           wl = nullptr;       n = CH*CH; break;
    case 2:  w = w2; wh = w34h;          wl = w34l;          n = CQ*CH; break;
    case 3:  w = w3; wh = w34h + CQ*CH;  wl = w34l + CQ*CH;  n = CQ*CH; break;
    default: w = w4; wh = w5h;           wl = nullptr;       n = CH*CH; break;
  }
  for (int i = blockIdx.x*blockDim.x + threadIdx.x; i < n; i += gridDim.x*blockDim.x){
    float v = w[i];
    u16 h = f2bf(v);
    wh[i] = h;
    if (wl) wl[i] = f2bf(v - bf2f(h));
  }
}

// zero a float4 range (qk_acc lives in the dead window of xh)
__global__ __launch_bounds__(256) void zero_f4(float4* __restrict__ p, int n4){
  const int i = blockIdx.x*blockDim.x + threadIdx.x;
  if (i < n4) p[i] = make_float4(0.f, 0.f, 0.f, 0.f);
}

// ---------------------------------------------------------------------------
// gemm_2ph: 256x256 tile, 8 waves (4M x 2N, per-wave 64x128), BK=64,
// minimum-2-phase pipeline: per K-tile { STAGE(next tile -> other buffer);
// ds_read + MFMA current; __syncthreads() }. Measured best structure for the
// three big GEMMs (round 3/6: attn 141.8-143.5us; geometry alternatives at
// 1/2/4 blocks-per-CU all measured worse). Swizzle chunk^(row&7)
// conflict-free (SQ_LDS_BANK_CONFLICT=0). Grid 256 = 8 batches (id&7, one
// per XCD) x 8 bx x 4 by; 1 block/CU.
// EPI 0: BN+relu (*cinv[row] col-div fold), bf16 store out[b][col][row] (conv2)
// EPI 1: attn: rowsum via colinv-MFMA; t = x1 - acc/rowsum, bf16 [b][row][col]
// EPI 2: BN+relu + x1 residual, fp32 store out[b][col][row]           (conv5)
// ---------------------------------------------------------------------------
template<int EPI>
__global__ __launch_bounds__(512, 2) void gemm_2ph(
    const u16* __restrict__ A, const u16* __restrict__ B,
    int lda, int ldb, long astr, long bstr, int K,
    void* __restrict__ out0, long ostr, int ldo,
    const float* __restrict__ pg, const float* __restrict__ pb,
    const float* __restrict__ pm, const float* __restrict__ pv,
    const u16* __restrict__ x1h, const u16* __restrict__ x1l,
    const float* __restrict__ cinv, const u16* __restrict__ cbf)
{
  __shared__ __align__(16) u16 sA[2][16384];   // 256 rows x 64 k, dbuf
  __shared__ __align__(16) u16 sB[2][16384];
  __shared__ __align__(16) u16 cl[2048];       // EPI1: colinv bf16 (K<=2048)

  const int tid  = threadIdx.x;
  const int lane = tid & 63;
  const int wave = tid >> 6;
  const int wr = wave >> 1, wc = wave & 1;     // 4M x 2N
  const int l15 = lane & 15, q = lane >> 4;
  const int id = blockIdx.x;
  const int bb = id & 7;
  const int rest = id >> 3;
  const int by = rest & 3;
  const int bx = rest >> 2;

  const u16* Ab = A + (size_t)bb*astr + (size_t)bx*256*lda;
  const u16* Bb = B + (size_t)bb*bstr + (size_t)by*256*ldb;

  const int sr0 = tid >> 3;                        // 0..63
  const int sg  = (((tid & 7) ^ (sr0 & 7)) << 3);  // pre-swizzled src chunk

  auto stage = [&](int kt, int bsel){
    u16* dA = sA[bsel]; u16* dB = sB[bsel];
#pragma unroll
    for (int rr = 0; rr < 4; ++rr){
      gl2lds16(Ab + (size_t)(rr*64 + sr0)*lda + kt + sg, dA + rr*4096 + tid*8);
      gl2lds16(Bb + (size_t)(rr*64 + sr0)*ldb + kt + sg, dB + rr*4096 + tid*8);
    }
  };

  int rpA[4], rpB[8];
#pragma unroll
  for (int i = 0; i < 4; ++i) rpA[i] = (wr*64 + i*16 + l15) << 6;
#pragma unroll
  for (int j = 0; j < 8; ++j) rpB[j] = (wc*128 + j*16 + l15) << 6;
  const int ckx = l15 & 7;
  const int ck0 = ((0 + q) ^ ckx) << 3;            // s=0 chunks 0..3
  const int ck1 = ((4 + q) ^ ckx) << 3;            // s=1 chunks 4..7

  if constexpr (EPI == 1){
    if (tid < 256)
      *(bf16x8*)&cl[tid*8] = *(const bf16x8*)&cbf[(size_t)bb*NP + tid*8];
  }

  f32x4 acc[4][8] = {};
  f32x4 accR[4] = {};

  const int NT = K >> 6;
  stage(0, 0);
  __syncthreads();

  for (int t = 0; t < NT; ++t){
    if (t + 1 < NT) stage((t + 1) << 6, (t + 1) & 1);   // issue BEFORE compute
    const u16* cA = sA[t & 1];
    const u16* cB = sB[t & 1];
    bf16x8 af[4], bfr[8];
    // ---- s = 0 ----
#pragma unroll
    for (int i = 0; i < 4; ++i) af[i]  = *(const bf16x8*)&cA[rpA[i] + ck0];
#pragma unroll
    for (int j = 0; j < 8; ++j) bfr[j] = *(const bf16x8*)&cB[rpB[j] + ck0];
    if constexpr (EPI == 1){
      const bf16x8 cbs = *(const bf16x8*)&cl[(t << 6) + q*8];
#pragma unroll
      for (int i = 0; i < 4; ++i)
        accR[i] = __builtin_amdgcn_mfma_f32_16x16x32_bf16(af[i], cbs, accR[i], 0, 0, 0);
    }
#pragma unroll
    for (int i = 0; i < 4; ++i)
#pragma unroll
      for (int j = 0; j < 8; ++j)
        acc[i][j] = __builtin_amdgcn_mfma_f32_16x16x32_bf16(af[i], bfr[j], acc[i][j], 0, 0, 0);
    // ---- s = 1 ----
#pragma unroll
    for (int i = 0; i < 4; ++i) af[i]  = *(const bf16x8*)&cA[rpA[i] + ck1];
#pragma unroll
    for (int j = 0; j < 8; ++j) bfr[j] = *(const bf16x8*)&cB[rpB[j] + ck1];
    if constexpr (EPI == 1){
      const bf16x8 cbs = *(const bf16x8*)&cl[(t << 6) + 32 + q*8];
#pragma unroll
      for (int i = 0; i < 4; ++i)
        accR[i] = __builtin_amdgcn_mfma_f32_16x16x32_bf16(af[i], cbs, accR[i], 0, 0, 0);
    }
#pragma unroll
    for (int i = 0; i < 4; ++i)
#pragma unroll
      for (int j = 0; j < 8; ++j)
        acc[i][j] = __builtin_amdgcn_mfma_f32_16x16x32_bf16(af[i], bfr[j], acc[i][j], 0, 0, 0);
    __syncthreads();
  }

  const int rbase = bx*256 + wr*64;
  const int cbase = by*256 + wc*128;
#pragma unroll
  for (int j = 0; j < 8; ++j){
    const int gc = cbase + j*16 + l15;
    float scale = 0.f, bias = 0.f;
    if (EPI == 0 || EPI == 2){
      scale = pg[gc] * rsqrtf(pv[gc] + 1e-5f);
      bias  = pb[gc] - pm[gc]*scale;
    }
#pragma unroll
    for (int i = 0; i < 4; ++i){
      const int gr0 = rbase + i*16 + q*4;
      if (EPI == 0){
        const float4 cv = *(const float4*)&cinv[(size_t)bb*NP + gr0];
        ushort4 pk;
        pk.x = f2bf(fmaxf(acc[i][j][0]*scale + bias, 0.f) * cv.x);
        pk.y = f2bf(fmaxf(acc[i][j][1]*scale + bias, 0.f) * cv.y);
        pk.z = f2bf(fmaxf(acc[i][j][2]*scale + bias, 0.f) * cv.z);
        pk.w = f2bf(fmaxf(acc[i][j][3]*scale + bias, 0.f) * cv.w);
        *(ushort4*)&((u16*)out0)[(size_t)bb*ostr + (size_t)gc*ldo + gr0] = pk;
      } else if (EPI == 1){
#pragma unroll
        for (int r = 0; r < 4; ++r){
          const int gr = gr0 + r;
          const size_t idx = (size_t)bb*ostr + (size_t)gr*ldo + gc;
          const float rsv = 1.f / (1e-9f + accR[i][r]);
          const float x1v = bf2f(x1h[idx]) + bf2f(x1l[idx]);
          ((u16*)out0)[idx] = f2bf(x1v - acc[i][j][r]*rsv);
        }
      } else {
        float4 o4;
#pragma unroll
        for (int r = 0; r < 4; ++r){
          const int gr = gr0 + r;
          const size_t xidx = (size_t)bb*((size_t)NP*CH) + (size_t)gr*CH + gc;
          const float x2  = fmaxf(acc[i][j][r]*scale + bias, 0.f);
          const float x1v = bf2f(x1h[xidx]) + bf2f(x1l[xidx]);
          (&o4.x)[r] = x1v + x2;
        }
        *(float4*)&((float*)out0)[(size_t)bb*ostr + (size_t)gc*ldo + gr0] = o4;
      }
    }
  }
}

// ---------------------------------------------------------------------------
// gemm_split_big: conv1 (split-precision) 256x256 tile, BK=32, 2-phase dbuf.
// ---------------------------------------------------------------------------
__global__ __launch_bounds__(512, 2) void gemm_split_big(
    const u16* __restrict__ Ah, const u16* __restrict__ Al,
    const u16* __restrict__ Bh, const u16* __restrict__ Bl,
    int lda, int ldb, long astr, long bstr, int K,
    u16* __restrict__ outH, u16* __restrict__ outL,
    long ostr, int ldo,
    const float* __restrict__ pg, const float* __restrict__ pb,
    const float* __restrict__ pm, const float* __restrict__ pv)
{
  __shared__ __align__(16) u16 sAh[2][8192], sAl[2][8192];   // 256 x 32
  __shared__ __align__(16) u16 sBh[2][8192], sBl[2][8192];

  const int tid  = threadIdx.x;
  const int lane = tid & 63;
  const int wave = tid >> 6;
  const int wr = wave >> 1, wc = wave & 1;
  const int l15 = lane & 15, q = lane >> 4;
  const int id = blockIdx.x;
  const int bb = id & 7;
  const int rest = id >> 3;
  const int by = rest & 3;
  const int bx = rest >> 2;

  const u16* Abh = Ah + (size_t)bb*astr + (size_t)bx*256*lda;
  const u16* Abl = Al + (size_t)bb*astr + (size_t)bx*256*lda;
  const u16* Bbh = Bh + (size_t)bb*bstr + (size_t)by*256*ldb;
  const u16* Bbl = Bl + (size_t)bb*bstr + (size_t)by*256*ldb;

  const int sr = tid >> 2;                              // 0..127
  const int sg = (((tid & 3) ^ ((sr >> 1) & 3)) << 3);  // pre-swizzled chunk

  auto stage = [&](int kt, int bsel){
    gl2lds16(Abh + (size_t)sr*lda        + kt + sg, &sAh[bsel][tid*8]);
    gl2lds16(Abh + (size_t)(sr+128)*lda  + kt + sg, &sAh[bsel][4096 + tid*8]);
    gl2lds16(Abl + (size_t)sr*lda        + kt + sg, &sAl[bsel][tid*8]);
    gl2lds16(Abl + (size_t)(sr+128)*lda  + kt + sg, &sAl[bsel][4096 + tid*8]);
    gl2lds16(Bbh + (size_t)sr*ldb        + kt + sg, &sBh[bsel][tid*8]);
    gl2lds16(Bbh + (size_t)(sr+128)*ldb  + kt + sg, &sBh[bsel][4096 + tid*8]);
    gl2lds16(Bbl + (size_t)sr*ldb        + kt + sg, &sBl[bsel][tid*8]);
    gl2lds16(Bbl + (size_t)(sr+128)*ldb  + kt + sg, &sBl[bsel][4096 + tid*8]);
  };

  int offA[4], offB[8];
#pragma unroll
  for (int i = 0; i < 4; ++i){
    const int ra = wr*64 + i*16 + l15;
    offA[i] = ra*32 + ((q ^ ((ra >> 1) & 3)) << 3);
  }
#pragma unroll
  for (int j = 0; j < 8; ++j){
    const int rb = wc*128 + j*16 + l15;
    offB[j] = rb*32 + ((q ^ ((rb >> 1) & 3)) << 3);
  }

  f32x4 acc[4][8] = {};

  const int NT = K >> 5;
  stage(0, 0);
  __syncthreads();

  for (int t = 0; t < NT; ++t){
    if (t + 1 < NT) stage((t + 1) << 5, (t + 1) & 1);
    const int cur = t & 1;
    bf16x8 ah[4], al2[4];
#pragma unroll
    for (int i = 0; i < 4; ++i){
      ah[i]  = *(const bf16x8*)&sAh[cur][offA[i]];
      al2[i] = *(const bf16x8*)&sAl[cur][offA[i]];
    }
#pragma unroll
    for (int jh = 0; jh < 2; ++jh){
      bf16x8 bh[4], bl[4];
#pragma unroll
      for (int j = 0; j < 4; ++j){
        bh[j] = *(const bf16x8*)&sBh[cur][offB[jh*4 + j]];
        bl[j] = *(const bf16x8*)&sBl[cur][offB[jh*4 + j]];
      }
#pragma unroll
      for (int i = 0; i < 4; ++i)
#pragma unroll
        for (int j = 0; j < 4; ++j){
          acc[i][jh*4+j] = __builtin_amdgcn_mfma_f32_16x16x32_bf16(ah[i],  bh[j], acc[i][jh*4+j], 0, 0, 0);
          acc[i][jh*4+j] = __builtin_amdgcn_mfma_f32_16x16x32_bf16(ah[i],  bl[j], acc[i][jh*4+j], 0, 0, 0);
          acc[i][jh*4+j] = __builtin_amdgcn_mfma_f32_16x16x32_bf16(al2[i], bh[j], acc[i][jh*4+j], 0, 0, 0);
        }
    }
    __syncthreads();
  }

  const int rbase = bx*256 + wr*64;
  const int cbase = by*256 + wc*128;
#pragma unroll
  for (int j = 0; j < 8; ++j){
    const int gc = cbase + j*16 + l15;
    const float scale = pg[gc] * rsqrtf(pv[gc] + 1e-5f);
    const float bias  = pb[gc] - pm[gc]*scale;
#pragma unroll
    for (int i = 0; i < 4; ++i){
      const int gr0 = rbase + i*16 + q*4;
#pragma unroll
      for (int r = 0; r < 4; ++r){
        const size_t idx = (size_t)bb*ostr + (size_t)(gr0 + r)*ldo + gc;
        const float y = fmaxf(acc[i][j][r]*scale + bias, 0.f);
        const u16 h = f2bf(y);
        outH[idx] = h;
        outL[idx] = f2bf(y - bf2f(h));
      }
    }
  }
}

// ---------------------------------------------------------------------------
// gemm_split_ksum: conv34 K-SPLIT (x4) version. 128x128 tile, K-chunk=256,
// grid 1024 = 8 batch x (16 bx x 2 by x 4 kc) -> 4 blocks/CU (32 KiB LDS).
// Rationale: old conv34 ran grid 256 = 1 block/CU and was staging-rate-bound
// (~73us for a tiny output); 4 blocks/CU raises ingest rate ~6 -> ~10.6
// B/cyc/CU (r0 measurement). Partial sums atomicAdd fp32 into qk_acc
// [b][n][256] (2 MB/batch -> L2-resident atomics). BN+relu+split happens in
// qk_fin AFTER summation (numerically identical to fused epilogue).
// ---------------------------------------------------------------------------
__global__ __launch_bounds__(256, 4) void gemm_split_ksum(
    const u16* __restrict__ Ah, const u16* __restrict__ Al,
    const u16* __restrict__ Bh, const u16* __restrict__ Bl,
    float* __restrict__ out)
{
  __shared__ __align__(16) u16 sAh[4096], sAl[4096], sBh[4096], sBl[4096];
  const int tid  = threadIdx.x;
  const int lane = tid & 63, wave = tid >> 6;
  const int wr = wave & 1, wc = wave >> 1;
  const int l15 = lane & 15, q = lane >> 4;
  const int id = blockIdx.x;
  const int bb = id & 7;
  const int rest = id >> 3;
  const int kc = rest & 3;
  const int r2 = rest >> 2;
  const int by = r2 & 1;
  const int bx = r2 >> 1;
  const int koff = kc << 8;                         // K-chunk base (256)

  const u16* Abh = Ah + (size_t)bb*((size_t)NP*CH) + (size_t)bx*128*CH;
  const u16* Abl = Al + (size_t)bb*((size_t)NP*CH) + (size_t)bx*128*CH;
  const u16* Bbh = Bh + (size_t)by*128*CH;
  const u16* Bbl = Bl + (size_t)by*128*CH;

  f32x4 acc[4][4] = {};

  const int r0 = tid >> 2, r1 = r0 + 64;
  const int cs = (((tid & 3) ^ ((r0 >> 1) & 3)) << 3);

  int offA[4], offB[4];
#pragma unroll
  for (int i = 0; i < 4; ++i){
    const int ra = wr*64 + i*16 + l15;
    offA[i] = ra*32 + ((q ^ ((ra >> 1) & 3)) << 3);
    const int rb = wc*64 + i*16 + l15;
    offB[i] = rb*32 + ((q ^ ((rb >> 1) & 3)) << 3);
  }

  for (int kt = 0; kt < 256; kt += 32){
    const int kk = koff + kt;
    gl2lds16(Abh + (size_t)r0*CH + kk + cs, &sAh[tid*8]);
    gl2lds16(Abh + (size_t)r1*CH + kk + cs, &sAh[2048 + tid*8]);
    gl2lds16(Abl + (size_t)r0*CH + kk + cs, &sAl[tid*8]);
    gl2lds16(Abl + (size_t)r1*CH + kk + cs, &sAl[2048 + tid*8]);
    gl2lds16(Bbh + (size_t)r0*CH + kk + cs, &sBh[tid*8]);
    gl2lds16(Bbh + (size_t)r1*CH + kk + cs, &sBh[2048 + tid*8]);
    gl2lds16(Bbl + (size_t)r0*CH + kk + cs, &sBl[tid*8]);
    gl2lds16(Bbl + (size_t)r1*CH + kk + cs, &sBl[2048 + tid*8]);
    __syncthreads();
    bf16x8 ah[4], al[4], bh2[4], bl2[4];
#pragma unroll
    for (int i = 0; i < 4; ++i){
      ah[i] = *(const bf16x8*)&sAh[offA[i]];
      al[i] = *(const bf16x8*)&sAl[offA[i]];
    }
#pragma unroll
    for (int j = 0; j < 4; ++j){
      bh2[j] = *(const bf16x8*)&sBh[offB[j]];
      bl2[j] = *(const bf16x8*)&sBl[offB[j]];
    }
#pragma unroll
    for (int i = 0; i < 4; ++i)
#pragma unroll
      for (int j = 0; j < 4; ++j){
        acc[i][j] = __builtin_amdgcn_mfma_f32_16x16x32_bf16(ah[i], bh2[j], acc[i][j], 0, 0, 0);
        acc[i][j] = __builtin_amdgcn_mfma_f32_16x16x32_bf16(ah[i], bl2[j], acc[i][j], 0, 0, 0);
        acc[i][j] = __builtin_amdgcn_mfma_f32_16x16x32_bf16(al[i], bh2[j], acc[i][j], 0, 0, 0);
      }
    __syncthreads();
  }

  const int rbase = bx*128 + wr*64;                  // n
  const int cbase = by*128 + wc*64;                  // out-channel (0..255)
#pragma unroll
  for (int j = 0; j < 4; ++j){
    const int gc = cbase + j*16 + l15;
#pragma unroll
    for (int i = 0; i < 4; ++i){
      const int gr0 = rbase + i*16 + q*4;
#pragma unroll
      for (int r = 0; r < 4; ++r)
        atomicAdd(&out[(size_t)bb*((size_t)NP*256) + (size_t)(gr0 + r)*256 + gc],
                  acc[i][j][r]);
    }
  }
}

// finalize qk: BN+relu on summed fp32, split bf16 store. One float4 / thread.
__global__ __launch_bounds__(256) void qk_fin(const float* __restrict__ acc,
                                              const float* __restrict__ p34,
                                              u16* __restrict__ qh,
                                              u16* __restrict__ ql){
  const int idx = blockIdx.x*256 + threadIdx.x;      // < 8*NP*256/4 = 1048576
  const int j0 = (idx*4) & 255;
  const float4 a = ((const float4*)acc)[idx];
  ushort4 h, l;
#pragma unroll
  for (int r = 0; r < 4; ++r){
    const int j = j0 + r;
    const float scale = p34[j] * rsqrtf(p34[768 + j] + 1e-5f);
    const float bias  = p34[256 + j] - p34[512 + j]*scale;
    const float y = fmaxf((&a.x)[r]*scale + bias, 0.f);
    const u16 hh = f2bf(y);
    (&h.x)[r] = hh;
    (&l.x)[r] = f2bf(y - bf2f(hh));
  }
  ((ushort4*)qh)[idx] = h;
  ((ushort4*)ql)[idx] = l;
}

// ---------------------------------------------------------------------------
// Split-bf16 GEMM (128x128): scores (EPI 1) — verified r3/r5 form.
// ---------------------------------------------------------------------------
template<int EPI>
__global__ __launch_bounds__(256, 4) void gemm_split3(
    const u16* __restrict__ Ah, const u16* __restrict__ Al,
    const u16* __restrict__ Bh, const u16* __restrict__ Bl,
    int lda, int ldb, long astr, long bstr, int K,
    u16* __restrict__ outH, u16* __restrict__ outL,
    long ostr, int ldo,
    const float* __restrict__ pg, const float* __restrict__ pb,
    const float* __restrict__ pm, const float* __restrict__ pv,
    float* __restrict__ colsum, int gymask, int gyshift)
{
  __shared__ __align__(16) u16 sAh[4096], sAl[4096], sBh[4096], sBl[4096];
  const int tid  = threadIdx.x;
  const int lane = tid & 63, wave = tid >> 6;
  const int wr = wave & 1, wc = wave >> 1;
  const int l15 = lane & 15, q = lane >> 4;
  const int id = blockIdx.x;
  const int bb = id & 7;
  const int rest = id >> 3;
  const int by = rest & gymask;
  const int bx = rest >> gyshift;
  const u16* Abh = Ah + (size_t)bb*astr + (size_t)bx*128*lda;
  const u16* Abl = Al + (size_t)bb*astr + (size_t)bx*128*lda;
  const u16* Bbh = Bh + (size_t)bb*bstr + (size_t)by*128*ldb;
  const u16* Bbl = Bl + (size_t)bb*bstr + (size_t)by*128*ldb;

  f32x4 acc[4][4] = {};

  const int r0 = tid >> 2, r1 = r0 + 64;
  const int cs = (((tid & 3) ^ ((r0 >> 1) & 3)) << 3);

  int offA[4], offB[4];
#pragma unroll
  for (int i = 0; i < 4; ++i){
    const int ra = wr*64 + i*16 + l15;
    offA[i] = ra*32 + ((q ^ ((ra >> 1) & 3)) << 3);
    const int rb = wc*64 + i*16 + l15;
    offB[i] = rb*32 + ((q ^ ((rb >> 1) & 3)) << 3);
  }

  for (int kt = 0; kt < K; kt += 32){
    gl2lds16(Abh + (size_t)r0*lda + kt + cs, &sAh[tid*8]);
    gl2lds16(Abh + (size_t)r1*lda + kt + cs, &sAh[2048 + tid*8]);
    gl2lds16(Abl + (size_t)r0*lda + kt + cs, &sAl[tid*8]);
    gl2lds16(Abl + (size_t)r1*lda + kt + cs, &sAl[2048 + tid*8]);
    gl2lds16(Bbh + (size_t)r0*ldb + kt + cs, &sBh[tid*8]);
    gl2lds16(Bbh + (size_t)r1*ldb + kt + cs, &sBh[2048 + tid*8]);
    gl2lds16(Bbl + (size_t)r0*ldb + kt + cs, &sBl[tid*8]);
    gl2lds16(Bbl + (size_t)r1*ldb + kt + cs, &sBl[2048 + tid*8]);
    __syncthreads();
    bf16x8 ah[4], al[4], bh2[4], bl2[4];
#pragma unroll
    for (int i = 0; i < 4; ++i){
      ah[i] = *(const bf16x8*)&sAh[offA[i]];
      al[i] = *(const bf16x8*)&sAl[offA[i]];
    }
#pragma unroll
    for (int j = 0; j < 4; ++j){
      bh2[j] = *(const bf16x8*)&sBh[offB[j]];
      bl2[j] = *(const bf16x8*)&sBl[offB[j]];
    }
#pragma unroll
    for (int i = 0; i < 4; ++i)
#pragma unroll
      for (int j = 0; j < 4; ++j){
        acc[i][j] = __builtin_amdgcn_mfma_f32_16x16x32_bf16(ah[i], bh2[j], acc[i][j], 0, 0, 0);
        acc[i][j] = __builtin_amdgcn_mfma_f32_16x16x32_bf16(ah[i], bl2[j], acc[i][j], 0, 0, 0);
        acc[i][j] = __builtin_amdgcn_mfma_f32_16x16x32_bf16(al[i], bh2[j], acc[i][j], 0, 0, 0);
      }
    __syncthreads();
  }

  const int rbase = bx*128 + wr*64;
  const int cbase = by*128 + wc*64;

  if constexpr (EPI == 1){
    __shared__ float colpart[128];
    if (tid < 128) colpart[tid] = 0.f;
    __syncthreads();
#pragma unroll
    for (int j = 0; j < 4; ++j){
      const int gc = cbase + j*16 + l15;
      float lsum = 0.f;
#pragma unroll
      for (int i = 0; i < 4; ++i){
        const int gr0 = rbase + i*16 + q*4;
#pragma unroll
        for (int r = 0; r < 4; ++r){
          const float e = __expf(fminf(acc[i][j][r], 85.f));  // scores >= 0
          outH[(size_t)bb*ostr + (size_t)(gr0 + r)*ldo + gc] = f2bf(e);
          lsum += e;
        }
      }
      atomicAdd(&colpart[wc*64 + j*16 + l15], lsum);
    }
    __syncthreads();
    if (tid < 128) atomicAdd(&colsum[(size_t)bb*NP + (size_t)by*128 + tid], colpart[tid]);
  } else {
#pragma unroll
    for (int j = 0; j < 4; ++j){
      const int gc = cbase + j*16 + l15;
      const float scale = pg[gc] * rsqrtf(pv[gc] + 1e-5f);
      const float bias  = pb[gc] - pm[gc]*scale;
#pragma unroll
      for (int i = 0; i < 4; ++i){
        const int gr0 = rbase + i*16 + q*4;
#pragma unroll
        for (int r = 0; r < 4; ++r){
          const size_t idx = (size_t)bb*ostr + (size_t)(gr0 + r)*ldo + gc;
          const float y = fmaxf(acc[i][j][r]*scale + bias, 0.f);
          const u16 h = f2bf(y);
          outH[idx] = h;
          outL[idx] = f2bf(y - bf2f(h));
        }
      }
    }
  }
}

// colinv = 1/colsum (fp32 + bf16 copies)
__global__ __launch_bounds__(256) void colinv_k(const float* __restrict__ cs,
                                                float* __restrict__ ci,
                                                u16* __restrict__ cib, int n){
  const int i = blockIdx.x*blockDim.x + threadIdx.x;
  if (i < n){
    const float v = 1.0f / cs[i];
    ci[i]  = v;
    cib[i] = f2bf(v);
  }
}

// ---------------------------------------------------------------------------
extern "C" void kernel_launch(void* const* d_in, const int* in_sizes, int n_in,
                              void* d_out, int out_size, void* d_ws, size_t ws_size,
                              hipStream_t stream){
  const float* x = (const float*)d_in[0];
  const float *W[5], *g[5], *bt[5], *mu[5], *vr[5];
  for (int i = 0; i < 5; ++i){
    W[i]  = (const float*)d_in[1 + 5*i + 0];
    g[i]  = (const float*)d_in[1 + 5*i + 1];
    bt[i] = (const float*)d_in[1 + 5*i + 2];
    mu[i] = (const float*)d_in[1 + 5*i + 3];
    vr[i] = (const float*)d_in[1 + 5*i + 4];
  }

  char* wp = (char*)d_ws;
  size_t off = 0;
  auto take = [&](size_t bytes) -> void* {
    void* p = wp + off;
    off = (off + bytes + 255) & ~(size_t)255;
    return p;
  };
  u16*   xh   = (u16*)take(33554432);   // x^T hi [b][n][c]; qk_acc (16MB) after
                                        // conv1; reused as v' [b][c][n] later
  u16*   xl   = (u16*)take(33554432);   // x^T lo;           reused as t [b][m][c]
  u16*   x1h  = (u16*)take(33554432);
  u16*   x1l  = (u16*)take(33554432);
  u16*   qkh  = (u16*)take(8388608);    // [b][n][256]: cols 0-127=q, 128-255=k
  u16*   qkl  = (u16*)take(8388608);
  float* csum = (float*)take(65536);    // colsum [b][n]
  float* cinv = (float*)take(65536);    // fp32 1/colsum
  u16*   cibf = (u16*)take(32768);      // bf16 1/colsum
  u16*   w1h  = (u16*)take(2097152);
  u16*   w1l  = (u16*)take(2097152);
  u16*   w2h  = (u16*)take(2097152);
  u16*   w34h = (u16*)take(524288);     // [256][1024] stacked W3;W4
  u16*   w34l = (u16*)take(524288);
  u16*   w5h  = (u16*)take(2097152);
  float* p34  = (float*)take(4096);     // g34|b34|m34|v34

  if (ws_size < off){
    ws_marker<<<1, 1, 0, stream>>>((float*)d_out, (float)(ws_size >> 20));
    return;
  }

  u16*   vh     = xh;          // x dead after conv1
  u16*   tt     = xl;
  float* qk_acc = (float*)xh;  // 16 MB fp32, lives in conv1-input dead window
  u16*   expS   = (u16*)d_out; // 64 MiB bf16 = d_out exactly; overwritten by conv5

  prep_all<<<dim3(256, 7), 256, 0, stream>>>(
      W[0], W[1], W[2], W[3], W[4],
      w1h, w1l, w2h, w34h, w34l, w5h,
      g[2], bt[2], mu[2], vr[2], g[3], bt[3], mu[3], vr[3],
      p34, csum);

  transpose_split<<<dim3(32,16,8), 256, 0, stream>>>(x, xh, xl);

  // conv1: x1 = cbr(x, W1)  (split precision)   256^2 tiles
  gemm_split_big<<<dim3(256), 512, 0, stream>>>(
      xh, xl, w1h, w1l, CH, CH, (long)NP*CH, 0, CH,
      x1h, x1l, (long)NP*CH, CH, g[0], bt[0], mu[0], vr[0]);

  // conv34 K-split: zero qk_acc (xh region, safe after conv1), 4 K-chunks at
  // 4 blocks/CU with fp32 atomics, then BN+relu+split finalize.
  zero_f4<<<dim3(4096), 256, 0, stream>>>((float4*)qk_acc, 8*NP*256/4);
  gemm_split_ksum<<<dim3(1024), 256, 0, stream>>>(
      x1h, x1l, w34h, w34l, qk_acc);
  qk_fin<<<dim3(4096), 256, 0, stream>>>(qk_acc, p34, qkh, qkl);

  // scores: expS[b][m][n] = exp(k_m . q_n) bf16 + column sums   grid 16x16x8
  gemm_split3<1><<<dim3(2048), 256, 0, stream>>>(
      qkh + 128, qkl + 128, qkh, qkl, 256, 256, (long)NP*256, (long)NP*256, CQ,
      expS, nullptr, (long)NP*NP, NP,
      nullptr, nullptr, nullptr, nullptr, csum, 15, 4);

  colinv_k<<<dim3(64), 256, 0, stream>>>(csum, cinv, cibf, 8*NP);

  // conv2: v' = cbr(x1, W2) * colinv[n]  -> vh [b][c][n]        grid 8x4x8
  gemm_2ph<0><<<dim3(256), 512, 0, stream>>>(
      x1h, w2h, CH, CH, (long)NP*CH, 0, CH,
      vh, (long)CH*NP, NP, g[1], bt[1], mu[1], vr[1],
      nullptr, nullptr, cinv, nullptr);

  // attn: acc = expS . v'; rowsum via colinv-MFMA; t = x1 - acc/rowsum
  gemm_2ph<1><<<dim3(256), 512, 0, stream>>>(
      expS, vh, NP, NP, (long)NP*NP, (long)CH*NP, NP,
      tt, (long)NP*CH, CH, nullptr, nullptr, nullptr, nullptr,
      x1h, x1l, nullptr, cibf);

  // conv5 + residual -> d_out fp32 [b][c][n]
  gemm_2ph<2><<<dim3(256), 512, 0, stream>>>(
      tt, w5h, CH, CH, (long)NP*CH, 0, CH,
      d_out, (long)CH*NP, NP, g[4], bt[4], mu[4], vr[4],
      x1h, x1l, nullptr, nullptr);
}

// Round 8
// 620.182 us; speedup vs baseline: 1.0389x; 1.0389x over previous
//
#include <hip/hip_runtime.h>

typedef unsigned short u16;
using bf16x8 = __attribute__((ext_vector_type(8))) short;
using f32x4  = __attribute__((ext_vector_type(4))) float;

#define CH   1024
#define NP   2048
#define CQ   128

__device__ __forceinline__ float bf2f(u16 u){
  union { unsigned u; float f; } c; c.u = ((unsigned)u) << 16; return c.f;
}
__device__ __forceinline__ u16 f2bf(float f){
  unsigned x = __float_as_uint(f);
  unsigned r = (x + 0x7fffu + ((x >> 16) & 1u)) >> 16;
  return (u16)r;
}

__device__ __forceinline__ void gl2lds16(const u16* g, u16* l){
  __builtin_amdgcn_global_load_lds(
      (const __attribute__((address_space(1))) unsigned int*)(const void*)g,
      (__attribute__((address_space(3))) unsigned int*)(void*)l,
      16, 0, 0);
}

__global__ void ws_marker(float* out, float have_mb){
  out[0] = 1048576.0f + have_mb;
}

// ---------------------------------------------------------------------------
// Transpose+split: x [b][c][n] fp32 -> xh,xl [b][n][c] bf16 (hi/lo split)
// ---------------------------------------------------------------------------
__global__ __launch_bounds__(256) void transpose_split(const float* __restrict__ x,
                                                       u16* __restrict__ xh,
                                                       u16* __restrict__ xl){
  const int bb = blockIdx.z;
  const int n0 = blockIdx.x * 64, c0 = blockIdx.y * 64;
  __shared__ float tile[64][65];
  const int t = threadIdx.x;
  const float* xb = x + ((size_t)bb*CH + c0)*NP + n0;
#pragma unroll
  for (int rr = 0; rr < 4; ++rr){
    const int c_l = (t >> 4) + rr*16;
    const int n_l = (t & 15) * 4;
    float4 v = *(const float4*)&xb[(size_t)c_l*NP + n_l];
    tile[c_l][n_l+0] = v.x; tile[c_l][n_l+1] = v.y;
    tile[c_l][n_l+2] = v.z; tile[c_l][n_l+3] = v.w;
  }
  __syncthreads();
  u16* oh = xh + ((size_t)bb*NP + n0)*CH + c0;
  u16* ol = xl + ((size_t)bb*NP + n0)*CH + c0;
#pragma unroll
  for (int rr = 0; rr < 4; ++rr){
    const int n_l = (t >> 4) + rr*16;
    const int c_l = (t & 15) * 4;
    ushort4 h, l;
    float v0 = tile[c_l+0][n_l], v1 = tile[c_l+1][n_l];
    float v2 = tile[c_l+2][n_l], v3 = tile[c_l+3][n_l];
    h.x = f2bf(v0); l.x = f2bf(v0 - bf2f(h.x));
    h.y = f2bf(v1); l.y = f2bf(v1 - bf2f(h.y));
    h.z = f2bf(v2); l.z = f2bf(v2 - bf2f(h.z));
    h.w = f2bf(v3); l.w = f2bf(v3 - bf2f(h.w));
    *(ushort4*)&oh[(size_t)n_l*CH + c_l] = h;
    *(ushort4*)&ol[(size_t)n_l*CH + c_l] = l;
  }
}

// ---------------------------------------------------------------------------
// Prep: weight splits (w3/w4 stacked), BN-param concat, colsum zero.
// ---------------------------------------------------------------------------
__global__ __launch_bounds__(256) void prep_all(
    const float* __restrict__ w0, const float* __restrict__ w1,
    const float* __restrict__ w2, const float* __restrict__ w3,
    const float* __restrict__ w4,
    u16* w1h, u16* w1l, u16* w2h,
    u16* w34h, u16* w34l, u16* w5h,
    const float* g3, const float* b3, const float* m3, const float* v3,
    const float* g4, const float* b4, const float* m4, const float* v4,
    float* p34, float* colsum){
  const int seg = blockIdx.y;
  if (seg == 5){
    for (int i = blockIdx.x*blockDim.x + threadIdx.x; i < 1024; i += gridDim.x*blockDim.x){
      const int grp = i >> 8, j = i & 255;
      const float* pa = (grp==0) ? g3 : (grp==1) ? b3 : (grp==2) ? m3 : v3;
      const float* pb = (grp==0) ? g4 : (grp==1) ? b4 : (grp==2) ? m4 : v4;
      p34[i] = (j < 128) ? pa[j] : pb[j-128];
    }
    return;
  }
  if (seg == 6){
    for (int i = blockIdx.x*blockDim.x + threadIdx.x; i < 8*NP; i += gridDim.x*blockDim.x)
      colsum[i] = 0.f;
    return;
  }
  const float* w; u16 *wh, *wl; int n;
  switch (seg){
    case 0:  w = w0; wh = w1h;           wl = w1l;           n = CH*CH; break;
    case 1:  w = w1; wh = w2h;           wl = nullptr;       n = CH*CH; break;
    case 2:  w = w2; wh = w34h;          wl = w34l;          n = CQ*CH; break;
    case 3:  w = w3; wh = w34h + CQ*CH;  wl = w34l + CQ*CH;  n = CQ*CH; break;
    default: w = w4; wh = w5h;           wl = nullptr;       n = CH*CH; break;
  }
  for (int i = blockIdx.x*blockDim.x + threadIdx.x; i < n; i += gridDim.x*blockDim.x){
    float v = w[i];
    u16 h = f2bf(v);
    wh[i] = h;
    if (wl) wl[i] = f2bf(v - bf2f(h));
  }
}

// ---------------------------------------------------------------------------
// gemm_2ph: 256x256 tile, 8 waves (4M x 2N, per-wave 64x128), BK=64,
// minimum-2-phase pipeline: per K-tile { STAGE(next tile -> other buffer);
// ds_read + MFMA current; __syncthreads() }. Measured best structure
// (attn 141.8-143.6 us across r3/r6/r7). Swizzle chunk^(row&7) conflict-free.
// Grid 256 = 8 batches (id&7, one per XCD) x 8 bx x 4 by; 1 block/CU.
// EPI 0: BN+relu (*cinv[row] col-div fold), bf16 store out[b][col][row] (conv2)
// EPI 1: attn: rowsum via colinv-MFMA; t = x1 - acc/rowsum, bf16 [b][row][col]
// EPI 2: BN+relu + x1 residual, fp32 store out[b][col][row]           (conv5)
// ---------------------------------------------------------------------------
template<int EPI>
__global__ __launch_bounds__(512, 2) void gemm_2ph(
    const u16* __restrict__ A, const u16* __restrict__ B,
    int lda, int ldb, long astr, long bstr, int K,
    void* __restrict__ out0, long ostr, int ldo,
    const float* __restrict__ pg, const float* __restrict__ pb,
    const float* __restrict__ pm, const float* __restrict__ pv,
    const u16* __restrict__ x1h, const u16* __restrict__ x1l,
    const float* __restrict__ cinv, const u16* __restrict__ cbf)
{
  __shared__ __align__(16) u16 sA[2][16384];   // 256 rows x 64 k, dbuf
  __shared__ __align__(16) u16 sB[2][16384];
  __shared__ __align__(16) u16 cl[2048];       // EPI1: colinv bf16 (K<=2048)

  const int tid  = threadIdx.x;
  const int lane = tid & 63;
  const int wave = tid >> 6;
  const int wr = wave >> 1, wc = wave & 1;     // 4M x 2N
  const int l15 = lane & 15, q = lane >> 4;
  const int id = blockIdx.x;
  const int bb = id & 7;
  const int rest = id >> 3;
  const int by = rest & 3;
  const int bx = rest >> 2;

  const u16* Ab = A + (size_t)bb*astr + (size_t)bx*256*lda;
  const u16* Bb = B + (size_t)bb*bstr + (size_t)by*256*ldb;

  const int sr0 = tid >> 3;                        // 0..63
  const int sg  = (((tid & 7) ^ (sr0 & 7)) << 3);  // pre-swizzled src chunk

  auto stage = [&](int kt, int bsel){
    u16* dA = sA[bsel]; u16* dB = sB[bsel];
#pragma unroll
    for (int rr = 0; rr < 4; ++rr){
      gl2lds16(Ab + (size_t)(rr*64 + sr0)*lda + kt + sg, dA + rr*4096 + tid*8);
      gl2lds16(Bb + (size_t)(rr*64 + sr0)*ldb + kt + sg, dB + rr*4096 + tid*8);
    }
  };

  int rpA[4], rpB[8];
#pragma unroll
  for (int i = 0; i < 4; ++i) rpA[i] = (wr*64 + i*16 + l15) << 6;
#pragma unroll
  for (int j = 0; j < 8; ++j) rpB[j] = (wc*128 + j*16 + l15) << 6;
  const int ckx = l15 & 7;
  const int ck0 = ((0 + q) ^ ckx) << 3;            // s=0 chunks 0..3
  const int ck1 = ((4 + q) ^ ckx) << 3;            // s=1 chunks 4..7

  if constexpr (EPI == 1){
    if (tid < 256)
      *(bf16x8*)&cl[tid*8] = *(const bf16x8*)&cbf[(size_t)bb*NP + tid*8];
  }

  f32x4 acc[4][8] = {};
  f32x4 accR[4] = {};

  const int NT = K >> 6;
  stage(0, 0);
  __syncthreads();

  for (int t = 0; t < NT; ++t){
    if (t + 1 < NT) stage((t + 1) << 6, (t + 1) & 1);   // issue BEFORE compute
    const u16* cA = sA[t & 1];
    const u16* cB = sB[t & 1];
    bf16x8 af[4], bfr[8];
    // ---- s = 0 ----
#pragma unroll
    for (int i = 0; i < 4; ++i) af[i]  = *(const bf16x8*)&cA[rpA[i] + ck0];
#pragma unroll
    for (int j = 0; j < 8; ++j) bfr[j] = *(const bf16x8*)&cB[rpB[j] + ck0];
    if constexpr (EPI == 1){
      const bf16x8 cbs = *(const bf16x8*)&cl[(t << 6) + q*8];
#pragma unroll
      for (int i = 0; i < 4; ++i)
        accR[i] = __builtin_amdgcn_mfma_f32_16x16x32_bf16(af[i], cbs, accR[i], 0, 0, 0);
    }
#pragma unroll
    for (int i = 0; i < 4; ++i)
#pragma unroll
      for (int j = 0; j < 8; ++j)
        acc[i][j] = __builtin_amdgcn_mfma_f32_16x16x32_bf16(af[i], bfr[j], acc[i][j], 0, 0, 0);
    // ---- s = 1 ----
#pragma unroll
    for (int i = 0; i < 4; ++i) af[i]  = *(const bf16x8*)&cA[rpA[i] + ck1];
#pragma unroll
    for (int j = 0; j < 8; ++j) bfr[j] = *(const bf16x8*)&cB[rpB[j] + ck1];
    if constexpr (EPI == 1){
      const bf16x8 cbs = *(const bf16x8*)&cl[(t << 6) + 32 + q*8];
#pragma unroll
      for (int i = 0; i < 4; ++i)
        accR[i] = __builtin_amdgcn_mfma_f32_16x16x32_bf16(af[i], cbs, accR[i], 0, 0, 0);
    }
#pragma unroll
    for (int i = 0; i < 4; ++i)
#pragma unroll
      for (int j = 0; j < 8; ++j)
        acc[i][j] = __builtin_amdgcn_mfma_f32_16x16x32_bf16(af[i], bfr[j], acc[i][j], 0, 0, 0);
    __syncthreads();
  }

  const int rbase = bx*256 + wr*64;
  const int cbase = by*256 + wc*128;
#pragma unroll
  for (int j = 0; j < 8; ++j){
    const int gc = cbase + j*16 + l15;
    float scale = 0.f, bias = 0.f;
    if (EPI == 0 || EPI == 2){
      scale = pg[gc] * rsqrtf(pv[gc] + 1e-5f);
      bias  = pb[gc] - pm[gc]*scale;
    }
#pragma unroll
    for (int i = 0; i < 4; ++i){
      const int gr0 = rbase + i*16 + q*4;
      if (EPI == 0){
        const float4 cv = *(const float4*)&cinv[(size_t)bb*NP + gr0];
        ushort4 pk;
        pk.x = f2bf(fmaxf(acc[i][j][0]*scale + bias, 0.f) * cv.x);
        pk.y = f2bf(fmaxf(acc[i][j][1]*scale + bias, 0.f) * cv.y);
        pk.z = f2bf(fmaxf(acc[i][j][2]*scale + bias, 0.f) * cv.z);
        pk.w = f2bf(fmaxf(acc[i][j][3]*scale + bias, 0.f) * cv.w);
        *(ushort4*)&((u16*)out0)[(size_t)bb*ostr + (size_t)gc*ldo + gr0] = pk;
      } else if (EPI == 1){
#pragma unroll
        for (int r = 0; r < 4; ++r){
          const int gr = gr0 + r;
          const size_t idx = (size_t)bb*ostr + (size_t)gr*ldo + gc;
          const float rsv = 1.f / (1e-9f + accR[i][r]);
          const float x1v = bf2f(x1h[idx]) + bf2f(x1l[idx]);
          ((u16*)out0)[idx] = f2bf(x1v - acc[i][j][r]*rsv);
        }
      } else {
        float4 o4;
#pragma unroll
        for (int r = 0; r < 4; ++r){
          const int gr = gr0 + r;
          const size_t xidx = (size_t)bb*((size_t)NP*CH) + (size_t)gr*CH + gc;
          const float x2  = fmaxf(acc[i][j][r]*scale + bias, 0.f);
          const float x1v = bf2f(x1h[xidx]) + bf2f(x1l[xidx]);
          (&o4.x)[r] = x1v + x2;
        }
        *(float4*)&((float*)out0)[(size_t)bb*ostr + (size_t)gc*ldo + gr0] = o4;
      }
    }
  }
}

// ---------------------------------------------------------------------------
// gemm_split_big: conv1 (split-precision) 256x256 tile, BK=32, 2-phase dbuf.
// ---------------------------------------------------------------------------
__global__ __launch_bounds__(512, 2) void gemm_split_big(
    const u16* __restrict__ Ah, const u16* __restrict__ Al,
    const u16* __restrict__ Bh, const u16* __restrict__ Bl,
    int lda, int ldb, long astr, long bstr, int K,
    u16* __restrict__ outH, u16* __restrict__ outL,
    long ostr, int ldo,
    const float* __restrict__ pg, const float* __restrict__ pb,
    const float* __restrict__ pm, const float* __restrict__ pv)
{
  __shared__ __align__(16) u16 sAh[2][8192], sAl[2][8192];   // 256 x 32
  __shared__ __align__(16) u16 sBh[2][8192], sBl[2][8192];

  const int tid  = threadIdx.x;
  const int lane = tid & 63;
  const int wave = tid >> 6;
  const int wr = wave >> 1, wc = wave & 1;
  const int l15 = lane & 15, q = lane >> 4;
  const int id = blockIdx.x;
  const int bb = id & 7;
  const int rest = id >> 3;
  const int by = rest & 3;
  const int bx = rest >> 2;

  const u16* Abh = Ah + (size_t)bb*astr + (size_t)bx*256*lda;
  const u16* Abl = Al + (size_t)bb*astr + (size_t)bx*256*lda;
  const u16* Bbh = Bh + (size_t)bb*bstr + (size_t)by*256*ldb;
  const u16* Bbl = Bl + (size_t)bb*bstr + (size_t)by*256*ldb;

  const int sr = tid >> 2;                              // 0..127
  const int sg = (((tid & 3) ^ ((sr >> 1) & 3)) << 3);  // pre-swizzled chunk

  auto stage = [&](int kt, int bsel){
    gl2lds16(Abh + (size_t)sr*lda        + kt + sg, &sAh[bsel][tid*8]);
    gl2lds16(Abh + (size_t)(sr+128)*lda  + kt + sg, &sAh[bsel][4096 + tid*8]);
    gl2lds16(Abl + (size_t)sr*lda        + kt + sg, &sAl[bsel][tid*8]);
    gl2lds16(Abl + (size_t)(sr+128)*lda  + kt + sg, &sAl[bsel][4096 + tid*8]);
    gl2lds16(Bbh + (size_t)sr*ldb        + kt + sg, &sBh[bsel][tid*8]);
    gl2lds16(Bbh + (size_t)(sr+128)*ldb  + kt + sg, &sBh[bsel][4096 + tid*8]);
    gl2lds16(Bbl + (size_t)sr*ldb        + kt + sg, &sBl[bsel][tid*8]);
    gl2lds16(Bbl + (size_t)(sr+128)*ldb  + kt + sg, &sBl[bsel][4096 + tid*8]);
  };

  int offA[4], offB[8];
#pragma unroll
  for (int i = 0; i < 4; ++i){
    const int ra = wr*64 + i*16 + l15;
    offA[i] = ra*32 + ((q ^ ((ra >> 1) & 3)) << 3);
  }
#pragma unroll
  for (int j = 0; j < 8; ++j){
    const int rb = wc*128 + j*16 + l15;
    offB[j] = rb*32 + ((q ^ ((rb >> 1) & 3)) << 3);
  }

  f32x4 acc[4][8] = {};

  const int NT = K >> 5;
  stage(0, 0);
  __syncthreads();

  for (int t = 0; t < NT; ++t){
    if (t + 1 < NT) stage((t + 1) << 5, (t + 1) & 1);
    const int cur = t & 1;
    bf16x8 ah[4], al2[4];
#pragma unroll
    for (int i = 0; i < 4; ++i){
      ah[i]  = *(const bf16x8*)&sAh[cur][offA[i]];
      al2[i] = *(const bf16x8*)&sAl[cur][offA[i]];
    }
#pragma unroll
    for (int jh = 0; jh < 2; ++jh){
      bf16x8 bh[4], bl[4];
#pragma unroll
      for (int j = 0; j < 4; ++j){
        bh[j] = *(const bf16x8*)&sBh[cur][offB[jh*4 + j]];
        bl[j] = *(const bf16x8*)&sBl[cur][offB[jh*4 + j]];
      }
#pragma unroll
      for (int i = 0; i < 4; ++i)
#pragma unroll
        for (int j = 0; j < 4; ++j){
          acc[i][jh*4+j] = __builtin_amdgcn_mfma_f32_16x16x32_bf16(ah[i],  bh[j], acc[i][jh*4+j], 0, 0, 0);
          acc[i][jh*4+j] = __builtin_amdgcn_mfma_f32_16x16x32_bf16(ah[i],  bl[j], acc[i][jh*4+j], 0, 0, 0);
          acc[i][jh*4+j] = __builtin_amdgcn_mfma_f32_16x16x32_bf16(al2[i], bh[j], acc[i][jh*4+j], 0, 0, 0);
        }
    }
    __syncthreads();
  }

  const int rbase = bx*256 + wr*64;
  const int cbase = by*256 + wc*128;
#pragma unroll
  for (int j = 0; j < 8; ++j){
    const int gc = cbase + j*16 + l15;
    const float scale = pg[gc] * rsqrtf(pv[gc] + 1e-5f);
    const float bias  = pb[gc] - pm[gc]*scale;
#pragma unroll
    for (int i = 0; i < 4; ++i){
      const int gr0 = rbase + i*16 + q*4;
#pragma unroll
      for (int r = 0; r < 4; ++r){
        const size_t idx = (size_t)bb*ostr + (size_t)(gr0 + r)*ldo + gc;
        const float y = fmaxf(acc[i][j][r]*scale + bias, 0.f);
        const u16 h = f2bf(y);
        outH[idx] = h;
        outL[idx] = f2bf(y - bf2f(h));
      }
    }
  }
}

// ---------------------------------------------------------------------------
// gemm_split_k4: conv34 K-SPLIT x4, NO ATOMICS. 128x128 tile, K-chunk=256,
// grid 1024 = 8 batch x (16 bx x 2 by x 4 kc) -> 4 blocks/CU (32 KiB LDS).
// Each kc block stores plain fp32 partials into its OWN 16 MB buffer
// (4 partials live in the xh+xl dead window: both dead between conv1 and
// conv2/attn). Lesson from r7: atomics cost +33us; disjoint buffers instead.
// qk_fin4 sums 4 partials + BN+relu + hi/lo split (coalesced float4 io).
// ---------------------------------------------------------------------------
__global__ __launch_bounds__(256, 4) void gemm_split_k4(
    const u16* __restrict__ Ah, const u16* __restrict__ Al,
    const u16* __restrict__ Bh, const u16* __restrict__ Bl,
    float* __restrict__ pA, float* __restrict__ pB)
{
  __shared__ __align__(16) u16 sAh[4096], sAl[4096], sBh[4096], sBl[4096];
  const int tid  = threadIdx.x;
  const int lane = tid & 63, wave = tid >> 6;
  const int wr = wave & 1, wc = wave >> 1;
  const int l15 = lane & 15, q = lane >> 4;
  const int id = blockIdx.x;
  const int bb = id & 7;
  const int rest = id >> 3;
  const int kc = rest & 3;
  const int r2 = rest >> 2;
  const int by = r2 & 1;
  const int bx = r2 >> 1;
  const int koff = kc << 8;                         // K-chunk base (256)

  const u16* Abh = Ah + (size_t)bb*((size_t)NP*CH) + (size_t)bx*128*CH;
  const u16* Abl = Al + (size_t)bb*((size_t)NP*CH) + (size_t)bx*128*CH;
  const u16* Bbh = Bh + (size_t)by*128*CH;
  const u16* Bbl = Bl + (size_t)by*128*CH;

  f32x4 acc[4][4] = {};

  const int r0 = tid >> 2, r1 = r0 + 64;
  const int cs = (((tid & 3) ^ ((r0 >> 1) & 3)) << 3);

  int offA[4], offB[4];
#pragma unroll
  for (int i = 0; i < 4; ++i){
    const int ra = wr*64 + i*16 + l15;
    offA[i] = ra*32 + ((q ^ ((ra >> 1) & 3)) << 3);
    const int rb = wc*64 + i*16 + l15;
    offB[i] = rb*32 + ((q ^ ((rb >> 1) & 3)) << 3);
  }

  for (int kt = 0; kt < 256; kt += 32){
    const int kk = koff + kt;
    gl2lds16(Abh + (size_t)r0*CH + kk + cs, &sAh[tid*8]);
    gl2lds16(Abh + (size_t)r1*CH + kk + cs, &sAh[2048 + tid*8]);
    gl2lds16(Abl + (size_t)r0*CH + kk + cs, &sAl[tid*8]);
    gl2lds16(Abl + (size_t)r1*CH + kk + cs, &sAl[2048 + tid*8]);
    gl2lds16(Bbh + (size_t)r0*CH + kk + cs, &sBh[tid*8]);
    gl2lds16(Bbh + (size_t)r1*CH + kk + cs, &sBh[2048 + tid*8]);
    gl2lds16(Bbl + (size_t)r0*CH + kk + cs, &sBl[tid*8]);
    gl2lds16(Bbl + (size_t)r1*CH + kk + cs, &sBl[2048 + tid*8]);
    __syncthreads();
    bf16x8 ah[4], al[4], bh2[4], bl2[4];
#pragma unroll
    for (int i = 0; i < 4; ++i){
      ah[i] = *(const bf16x8*)&sAh[offA[i]];
      al[i] = *(const bf16x8*)&sAl[offA[i]];
    }
#pragma unroll
    for (int j = 0; j < 4; ++j){
      bh2[j] = *(const bf16x8*)&sBh[offB[j]];
      bl2[j] = *(const bf16x8*)&sBl[offB[j]];
    }
#pragma unroll
    for (int i = 0; i < 4; ++i)
#pragma unroll
      for (int j = 0; j < 4; ++j){
        acc[i][j] = __builtin_amdgcn_mfma_f32_16x16x32_bf16(ah[i], bh2[j], acc[i][j], 0, 0, 0);
        acc[i][j] = __builtin_amdgcn_mfma_f32_16x16x32_bf16(ah[i], bl2[j], acc[i][j], 0, 0, 0);
        acc[i][j] = __builtin_amdgcn_mfma_f32_16x16x32_bf16(al[i], bh2[j], acc[i][j], 0, 0, 0);
      }
    __syncthreads();
  }

  // partial buffer for this kc (no atomics): kc 0,1 in pA; 2,3 in pB.
  float* out = ((kc & 2) ? pB : pA) + (size_t)(kc & 1)*((size_t)8*NP*256)
             + (size_t)bb*((size_t)NP*256);

  const int rbase = bx*128 + wr*64;                  // n
  const int cbase = by*128 + wc*64;                  // out-channel (0..255)
#pragma unroll
  for (int j = 0; j < 4; ++j){
    const int gc = cbase + j*16 + l15;
#pragma unroll
    for (int i = 0; i < 4; ++i){
      const int gr0 = rbase + i*16 + q*4;
#pragma unroll
      for (int r = 0; r < 4; ++r)
        out[(size_t)(gr0 + r)*256 + gc] = acc[i][j][r];
    }
  }
}

// finalize qk: sum 4 partials, BN+relu, split bf16. One float4 / thread.
__global__ __launch_bounds__(256) void qk_fin4(const float* __restrict__ pA,
                                               const float* __restrict__ pB,
                                               const float* __restrict__ p34,
                                               u16* __restrict__ qh,
                                               u16* __restrict__ ql){
  const int idx = blockIdx.x*256 + threadIdx.x;      // < 8*NP*256/4 = 1048576
  const size_t S = (size_t)8*NP*256/4;               // partial size in float4
  const int j0 = (idx*4) & 255;
  const float4 a0 = ((const float4*)pA)[idx];
  const float4 a1 = ((const float4*)pA)[idx + S];
  const float4 a2 = ((const float4*)pB)[idx];
  const float4 a3 = ((const float4*)pB)[idx + S];
  ushort4 h, l;
#pragma unroll
  for (int r = 0; r < 4; ++r){
    const int j = j0 + r;
    const float s = (&a0.x)[r] + (&a1.x)[r] + (&a2.x)[r] + (&a3.x)[r];
    const float scale = p34[j] * rsqrtf(p34[768 + j] + 1e-5f);
    const float bias  = p34[256 + j] - p34[512 + j]*scale;
    const float y = fmaxf(s*scale + bias, 0.f);
    const u16 hh = f2bf(y);
    (&h.x)[r] = hh;
    (&l.x)[r] = f2bf(y - bf2f(hh));
  }
  ((ushort4*)qh)[idx] = h;
  ((ushort4*)ql)[idx] = l;
}

// ---------------------------------------------------------------------------
// Split-bf16 GEMM (128x128): scores (EPI 1) — verified r3 form.
// ---------------------------------------------------------------------------
template<int EPI>
__global__ __launch_bounds__(256, 4) void gemm_split3(
    const u16* __restrict__ Ah, const u16* __restrict__ Al,
    const u16* __restrict__ Bh, const u16* __restrict__ Bl,
    int lda, int ldb, long astr, long bstr, int K,
    u16* __restrict__ outH, u16* __restrict__ outL,
    long ostr, int ldo,
    const float* __restrict__ pg, const float* __restrict__ pb,
    const float* __restrict__ pm, const float* __restrict__ pv,
    float* __restrict__ colsum, int gymask, int gyshift)
{
  __shared__ __align__(16) u16 sAh[4096], sAl[4096], sBh[4096], sBl[4096];
  const int tid  = threadIdx.x;
  const int lane = tid & 63, wave = tid >> 6;
  const int wr = wave & 1, wc = wave >> 1;
  const int l15 = lane & 15, q = lane >> 4;
  const int id = blockIdx.x;
  const int bb = id & 7;
  const int rest = id >> 3;
  const int by = rest & gymask;
  const int bx = rest >> gyshift;
  const u16* Abh = Ah + (size_t)bb*astr + (size_t)bx*128*lda;
  const u16* Abl = Al + (size_t)bb*astr + (size_t)bx*128*lda;
  const u16* Bbh = Bh + (size_t)bb*bstr + (size_t)by*128*ldb;
  const u16* Bbl = Bl + (size_t)bb*bstr + (size_t)by*128*ldb;

  f32x4 acc[4][4] = {};

  const int r0 = tid >> 2, r1 = r0 + 64;
  const int cs = (((tid & 3) ^ ((r0 >> 1) & 3)) << 3);

  int offA[4], offB[4];
#pragma unroll
  for (int i = 0; i < 4; ++i){
    const int ra = wr*64 + i*16 + l15;
    offA[i] = ra*32 + ((q ^ ((ra >> 1) & 3)) << 3);
    const int rb = wc*64 + i*16 + l15;
    offB[i] = rb*32 + ((q ^ ((rb >> 1) & 3)) << 3);
  }

  for (int kt = 0; kt < K; kt += 32){
    gl2lds16(Abh + (size_t)r0*lda + kt + cs, &sAh[tid*8]);
    gl2lds16(Abh + (size_t)r1*lda + kt + cs, &sAh[2048 + tid*8]);
    gl2lds16(Abl + (size_t)r0*lda + kt + cs, &sAl[tid*8]);
    gl2lds16(Abl + (size_t)r1*lda + kt + cs, &sAl[2048 + tid*8]);
    gl2lds16(Bbh + (size_t)r0*ldb + kt + cs, &sBh[tid*8]);
    gl2lds16(Bbh + (size_t)r1*ldb + kt + cs, &sBh[2048 + tid*8]);
    gl2lds16(Bbl + (size_t)r0*ldb + kt + cs, &sBl[tid*8]);
    gl2lds16(Bbl + (size_t)r1*ldb + kt + cs, &sBl[2048 + tid*8]);
    __syncthreads();
    bf16x8 ah[4], al[4], bh2[4], bl2[4];
#pragma unroll
    for (int i = 0; i < 4; ++i){
      ah[i] = *(const bf16x8*)&sAh[offA[i]];
      al[i] = *(const bf16x8*)&sAl[offA[i]];
    }
#pragma unroll
    for (int j = 0; j < 4; ++j){
      bh2[j] = *(const bf16x8*)&sBh[offB[j]];
      bl2[j] = *(const bf16x8*)&sBl[offB[j]];
    }
#pragma unroll
    for (int i = 0; i < 4; ++i)
#pragma unroll
      for (int j = 0; j < 4; ++j){
        acc[i][j] = __builtin_amdgcn_mfma_f32_16x16x32_bf16(ah[i], bh2[j], acc[i][j], 0, 0, 0);
        acc[i][j] = __builtin_amdgcn_mfma_f32_16x16x32_bf16(ah[i], bl2[j], acc[i][j], 0, 0, 0);
        acc[i][j] = __builtin_amdgcn_mfma_f32_16x16x32_bf16(al[i], bh2[j], acc[i][j], 0, 0, 0);
      }
    __syncthreads();
  }

  const int rbase = bx*128 + wr*64;
  const int cbase = by*128 + wc*64;

  if constexpr (EPI == 1){
    __shared__ float colpart[128];
    if (tid < 128) colpart[tid] = 0.f;
    __syncthreads();
#pragma unroll
    for (int j = 0; j < 4; ++j){
      const int gc = cbase + j*16 + l15;
      float lsum = 0.f;
#pragma unroll
      for (int i = 0; i < 4; ++i){
        const int gr0 = rbase + i*16 + q*4;
#pragma unroll
        for (int r = 0; r < 4; ++r){
          const float e = __expf(fminf(acc[i][j][r], 85.f));  // scores >= 0
          outH[(size_t)bb*ostr + (size_t)(gr0 + r)*ldo + gc] = f2bf(e);
          lsum += e;
        }
      }
      atomicAdd(&colpart[wc*64 + j*16 + l15], lsum);
    }
    __syncthreads();
    if (tid < 128) atomicAdd(&colsum[(size_t)bb*NP + (size_t)by*128 + tid], colpart[tid]);
  } else {
#pragma unroll
    for (int j = 0; j < 4; ++j){
      const int gc = cbase + j*16 + l15;
      const float scale = pg[gc] * rsqrtf(pv[gc] + 1e-5f);
      const float bias  = pb[gc] - pm[gc]*scale;
#pragma unroll
      for (int i = 0; i < 4; ++i){
        const int gr0 = rbase + i*16 + q*4;
#pragma unroll
        for (int r = 0; r < 4; ++r){
          const size_t idx = (size_t)bb*ostr + (size_t)(gr0 + r)*ldo + gc;
          const float y = fmaxf(acc[i][j][r]*scale + bias, 0.f);
          const u16 h = f2bf(y);
          outH[idx] = h;
          outL[idx] = f2bf(y - bf2f(h));
        }
      }
    }
  }
}

// colinv = 1/colsum (fp32 + bf16 copies)
__global__ __launch_bounds__(256) void colinv_k(const float* __restrict__ cs,
                                                float* __restrict__ ci,
                                                u16* __restrict__ cib, int n){
  const int i = blockIdx.x*blockDim.x + threadIdx.x;
  if (i < n){
    const float v = 1.0f / cs[i];
    ci[i]  = v;
    cib[i] = f2bf(v);
  }
}

// ---------------------------------------------------------------------------
extern "C" void kernel_launch(void* const* d_in, const int* in_sizes, int n_in,
                              void* d_out, int out_size, void* d_ws, size_t ws_size,
                              hipStream_t stream){
  const float* x = (const float*)d_in[0];
  const float *W[5], *g[5], *bt[5], *mu[5], *vr[5];
  for (int i = 0; i < 5; ++i){
    W[i]  = (const float*)d_in[1 + 5*i + 0];
    g[i]  = (const float*)d_in[1 + 5*i + 1];
    bt[i] = (const float*)d_in[1 + 5*i + 2];
    mu[i] = (const float*)d_in[1 + 5*i + 3];
    vr[i] = (const float*)d_in[1 + 5*i + 4];
  }

  char* wp = (char*)d_ws;
  size_t off = 0;
  auto take = [&](size_t bytes) -> void* {
    void* p = wp + off;
    off = (off + bytes + 255) & ~(size_t)255;
    return p;
  };
  u16*   xh   = (u16*)take(33554432);   // x^T hi [b][n][c]; qk partials 0,1
                                        // after conv1; v' [b][c][n] after
  u16*   xl   = (u16*)take(33554432);   // x^T lo; qk partials 2,3; tt after
  u16*   x1h  = (u16*)take(33554432);
  u16*   x1l  = (u16*)take(33554432);
  u16*   qkh  = (u16*)take(8388608);    // [b][n][256]: cols 0-127=q, 128-255=k
  u16*   qkl  = (u16*)take(8388608);
  float* csum = (float*)take(65536);    // colsum [b][n]
  float* cinv = (float*)take(65536);    // fp32 1/colsum
  u16*   cibf = (u16*)take(32768);      // bf16 1/colsum
  u16*   w1h  = (u16*)take(2097152);
  u16*   w1l  = (u16*)take(2097152);
  u16*   w2h  = (u16*)take(2097152);
  u16*   w34h = (u16*)take(524288);     // [256][1024] stacked W3;W4
  u16*   w34l = (u16*)take(524288);
  u16*   w5h  = (u16*)take(2097152);
  float* p34  = (float*)take(4096);     // g34|b34|m34|v34

  if (ws_size < off){
    ws_marker<<<1, 1, 0, stream>>>((float*)d_out, (float)(ws_size >> 20));
    return;
  }

  u16*   vh   = xh;            // x dead after conv1
  u16*   tt   = xl;
  float* prtA = (float*)xh;    // qk partials kc=0,1 (32 MB, conv1-dead window)
  float* prtB = (float*)xl;    // qk partials kc=2,3
  u16*   expS = (u16*)d_out;   // 64 MiB bf16 = d_out exactly; overwritten by conv5

  prep_all<<<dim3(256, 7), 256, 0, stream>>>(
      W[0], W[1], W[2], W[3], W[4],
      w1h, w1l, w2h, w34h, w34l, w5h,
      g[2], bt[2], mu[2], vr[2], g[3], bt[3], mu[3], vr[3],
      p34, csum);

  transpose_split<<<dim3(32,16,8), 256, 0, stream>>>(x, xh, xl);

  // conv1: x1 = cbr(x, W1)  (split precision)   256^2 tiles
  gemm_split_big<<<dim3(256), 512, 0, stream>>>(
      xh, xl, w1h, w1l, CH, CH, (long)NP*CH, 0, CH,
      x1h, x1l, (long)NP*CH, CH, g[0], bt[0], mu[0], vr[0]);

  // conv34 K-split x4, no atomics: 4 blocks/CU, disjoint fp32 partials in
  // the xh+xl dead window, then sum+BN+relu+split finalize.
  gemm_split_k4<<<dim3(1024), 256, 0, stream>>>(
      x1h, x1l, w34h, w34l, prtA, prtB);
  qk_fin4<<<dim3(4096), 256, 0, stream>>>(prtA, prtB, p34, qkh, qkl);

  // scores: expS[b][m][n] = exp(k_m . q_n) bf16 + column sums   grid 16x16x8
  gemm_split3<1><<<dim3(2048), 256, 0, stream>>>(
      qkh + 128, qkl + 128, qkh, qkl, 256, 256, (long)NP*256, (long)NP*256, CQ,
      expS, nullptr, (long)NP*NP, NP,
      nullptr, nullptr, nullptr, nullptr, csum, 15, 4);

  colinv_k<<<dim3(64), 256, 0, stream>>>(csum, cinv, cibf, 8*NP);

  // conv2: v' = cbr(x1, W2) * colinv[n]  -> vh [b][c][n]        grid 8x4x8
  gemm_2ph<0><<<dim3(256), 512, 0, stream>>>(
      x1h, w2h, CH, CH, (long)NP*CH, 0, CH,
      vh, (long)CH*NP, NP, g[1], bt[1], mu[1], vr[1],
      nullptr, nullptr, cinv, nullptr);

  // attn: acc = expS . v'; rowsum via colinv-MFMA; t = x1 - acc/rowsum
  gemm_2ph<1><<<dim3(256), 512, 0, stream>>>(
      expS, vh, NP, NP, (long)NP*NP, (long)CH*NP, NP,
      tt, (long)NP*CH, CH, nullptr, nullptr, nullptr, nullptr,
      x1h, x1l, nullptr, cibf);

  // conv5 + residual -> d_out fp32 [b][c][n]
  gemm_2ph<2><<<dim3(256), 512, 0, stream>>>(
      tt, w5h, CH, CH, (long)NP*CH, 0, CH,
      d_out, (long)CH*NP, NP, g[4], bt[4], mu[4], vr[4],
      x1h, x1l, nullptr, nullptr);
}

// Round 9
// 597.212 us; speedup vs baseline: 1.0789x; 1.0385x over previous
//
#include <hip/hip_runtime.h>

typedef unsigned short u16;
using bf16x8 = __attribute__((ext_vector_type(8))) short;
using f32x4  = __attribute__((ext_vector_type(4))) float;

#define CH   1024
#define NP   2048
#define CQ   128

__device__ __forceinline__ float bf2f(u16 u){
  union { unsigned u; float f; } c; c.u = ((unsigned)u) << 16; return c.f;
}
__device__ __forceinline__ u16 f2bf(float f){
  unsigned x = __float_as_uint(f);
  unsigned r = (x + 0x7fffu + ((x >> 16) & 1u)) >> 16;
  return (u16)r;
}

__device__ __forceinline__ void gl2lds16(const u16* g, u16* l){
  __builtin_amdgcn_global_load_lds(
      (const __attribute__((address_space(1))) unsigned int*)(const void*)g,
      (__attribute__((address_space(3))) unsigned int*)(void*)l,
      16, 0, 0);
}

__global__ void ws_marker(float* out, float have_mb){
  out[0] = 1048576.0f + have_mb;
}

// ---------------------------------------------------------------------------
// Transpose+split: x [b][c][n] fp32 -> xh,xl [b][n][c] bf16 (hi/lo split)
// ---------------------------------------------------------------------------
__global__ __launch_bounds__(256) void transpose_split(const float* __restrict__ x,
                                                       u16* __restrict__ xh,
                                                       u16* __restrict__ xl){
  const int bb = blockIdx.z;
  const int n0 = blockIdx.x * 64, c0 = blockIdx.y * 64;
  __shared__ float tile[64][65];
  const int t = threadIdx.x;
  const float* xb = x + ((size_t)bb*CH + c0)*NP + n0;
#pragma unroll
  for (int rr = 0; rr < 4; ++rr){
    const int c_l = (t >> 4) + rr*16;
    const int n_l = (t & 15) * 4;
    float4 v = *(const float4*)&xb[(size_t)c_l*NP + n_l];
    tile[c_l][n_l+0] = v.x; tile[c_l][n_l+1] = v.y;
    tile[c_l][n_l+2] = v.z; tile[c_l][n_l+3] = v.w;
  }
  __syncthreads();
  u16* oh = xh + ((size_t)bb*NP + n0)*CH + c0;
  u16* ol = xl + ((size_t)bb*NP + n0)*CH + c0;
#pragma unroll
  for (int rr = 0; rr < 4; ++rr){
    const int n_l = (t >> 4) + rr*16;
    const int c_l = (t & 15) * 4;
    ushort4 h, l;
    float v0 = tile[c_l+0][n_l], v1 = tile[c_l+1][n_l];
    float v2 = tile[c_l+2][n_l], v3 = tile[c_l+3][n_l];
    h.x = f2bf(v0); l.x = f2bf(v0 - bf2f(h.x));
    h.y = f2bf(v1); l.y = f2bf(v1 - bf2f(h.y));
    h.z = f2bf(v2); l.z = f2bf(v2 - bf2f(h.z));
    h.w = f2bf(v3); l.w = f2bf(v3 - bf2f(h.w));
    *(ushort4*)&oh[(size_t)n_l*CH + c_l] = h;
    *(ushort4*)&ol[(size_t)n_l*CH + c_l] = l;
  }
}

// ---------------------------------------------------------------------------
// Prep: weight splits (w3/w4 stacked), BN-param concat, colsum zero.
// ---------------------------------------------------------------------------
__global__ __launch_bounds__(256) void prep_all(
    const float* __restrict__ w0, const float* __restrict__ w1,
    const float* __restrict__ w2, const float* __restrict__ w3,
    const float* __restrict__ w4,
    u16* w1h, u16* w1l, u16* w2h,
    u16* w34h, u16* w34l, u16* w5h,
    const float* g3, const float* b3, const float* m3, const float* v3,
    const float* g4, const float* b4, const float* m4, const float* v4,
    float* p34, float* colsum){
  const int seg = blockIdx.y;
  if (seg == 5){
    for (int i = blockIdx.x*blockDim.x + threadIdx.x; i < 1024; i += gridDim.x*blockDim.x){
      const int grp = i >> 8, j = i & 255;
      const float* pa = (grp==0) ? g3 : (grp==1) ? b3 : (grp==2) ? m3 : v3;
      const float* pb = (grp==0) ? g4 : (grp==1) ? b4 : (grp==2) ? m4 : v4;
      p34[i] = (j < 128) ? pa[j] : pb[j-128];
    }
    return;
  }
  if (seg == 6){
    for (int i = blockIdx.x*blockDim.x + threadIdx.x; i < 8*NP; i += gridDim.x*blockDim.x)
      colsum[i] = 0.f;
    return;
  }
  const float* w; u16 *wh, *wl; int n;
  switch (seg){
    case 0:  w = w0; wh = w1h;           wl = w1l;           n = CH*CH; break;
    case 1:  w = w1; wh = w2h;           wl = nullptr;       n = CH*CH; break;
    case 2:  w = w2; wh = w34h;          wl = w34l;          n = CQ*CH; break;
    case 3:  w = w3; wh = w34h + CQ*CH;  wl = w34l + CQ*CH;  n = CQ*CH; break;
    default: w = w4; wh = w5h;           wl = nullptr;       n = CH*CH; break;
  }
  for (int i = blockIdx.x*blockDim.x + threadIdx.x; i < n; i += gridDim.x*blockDim.x){
    float v = w[i];
    u16 h = f2bf(v);
    wh[i] = h;
    if (wl) wl[i] = f2bf(v - bf2f(h));
  }
}

// ---------------------------------------------------------------------------
// gemm_2ph: 256x256 tile, 8 waves (4M x 2N, per-wave 64x128), BK=64,
// minimum-2-phase pipeline: per K-tile { STAGE(next tile -> other buffer);
// ds_read + MFMA current; __syncthreads() }. Measured best structure
// (attn 141.5-143.6 us across r3/r6/r7/r8). Swizzle chunk^(row&7)
// conflict-free (SQ_LDS_BANK_CONFLICT=0). Grid 256 = 8 batches (id&7, one
// per XCD) x 8 bx x 4 by; 1 block/CU.
// EPI 0: BN+relu (*cinv[row] col-div fold), bf16 store out[b][col][row] (conv2)
// EPI 1: attn: rowsum via colinv-MFMA; t = x1 - acc/rowsum, bf16 [b][row][col]
// EPI 2: BN+relu + x1 residual, fp32 store out[b][col][row]           (conv5)
// ---------------------------------------------------------------------------
template<int EPI>
__global__ __launch_bounds__(512, 2) void gemm_2ph(
    const u16* __restrict__ A, const u16* __restrict__ B,
    int lda, int ldb, long astr, long bstr, int K,
    void* __restrict__ out0, long ostr, int ldo,
    const float* __restrict__ pg, const float* __restrict__ pb,
    const float* __restrict__ pm, const float* __restrict__ pv,
    const u16* __restrict__ x1h, const u16* __restrict__ x1l,
    const float* __restrict__ cinv, const u16* __restrict__ cbf)
{
  __shared__ __align__(16) u16 sA[2][16384];   // 256 rows x 64 k, dbuf
  __shared__ __align__(16) u16 sB[2][16384];
  __shared__ __align__(16) u16 cl[2048];       // EPI1: colinv bf16 (K<=2048)

  const int tid  = threadIdx.x;
  const int lane = tid & 63;
  const int wave = tid >> 6;
  const int wr = wave >> 1, wc = wave & 1;     // 4M x 2N
  const int l15 = lane & 15, q = lane >> 4;
  const int id = blockIdx.x;
  const int bb = id & 7;
  const int rest = id >> 3;
  const int by = rest & 3;
  const int bx = rest >> 2;

  const u16* Ab = A + (size_t)bb*astr + (size_t)bx*256*lda;
  const u16* Bb = B + (size_t)bb*bstr + (size_t)by*256*ldb;

  const int sr0 = tid >> 3;                        // 0..63
  const int sg  = (((tid & 7) ^ (sr0 & 7)) << 3);  // pre-swizzled src chunk

  auto stage = [&](int kt, int bsel){
    u16* dA = sA[bsel]; u16* dB = sB[bsel];
#pragma unroll
    for (int rr = 0; rr < 4; ++rr){
      gl2lds16(Ab + (size_t)(rr*64 + sr0)*lda + kt + sg, dA + rr*4096 + tid*8);
      gl2lds16(Bb + (size_t)(rr*64 + sr0)*ldb + kt + sg, dB + rr*4096 + tid*8);
    }
  };

  int rpA[4], rpB[8];
#pragma unroll
  for (int i = 0; i < 4; ++i) rpA[i] = (wr*64 + i*16 + l15) << 6;
#pragma unroll
  for (int j = 0; j < 8; ++j) rpB[j] = (wc*128 + j*16 + l15) << 6;
  const int ckx = l15 & 7;
  const int ck0 = ((0 + q) ^ ckx) << 3;            // s=0 chunks 0..3
  const int ck1 = ((4 + q) ^ ckx) << 3;            // s=1 chunks 4..7

  if constexpr (EPI == 1){
    if (tid < 256)
      *(bf16x8*)&cl[tid*8] = *(const bf16x8*)&cbf[(size_t)bb*NP + tid*8];
  }

  f32x4 acc[4][8] = {};
  f32x4 accR[4] = {};

  const int NT = K >> 6;
  stage(0, 0);
  __syncthreads();

  for (int t = 0; t < NT; ++t){
    if (t + 1 < NT) stage((t + 1) << 6, (t + 1) & 1);   // issue BEFORE compute
    const u16* cA = sA[t & 1];
    const u16* cB = sB[t & 1];
    bf16x8 af[4], bfr[8];
    // ---- s = 0 ----
#pragma unroll
    for (int i = 0; i < 4; ++i) af[i]  = *(const bf16x8*)&cA[rpA[i] + ck0];
#pragma unroll
    for (int j = 0; j < 8; ++j) bfr[j] = *(const bf16x8*)&cB[rpB[j] + ck0];
    if constexpr (EPI == 1){
      const bf16x8 cbs = *(const bf16x8*)&cl[(t << 6) + q*8];
#pragma unroll
      for (int i = 0; i < 4; ++i)
        accR[i] = __builtin_amdgcn_mfma_f32_16x16x32_bf16(af[i], cbs, accR[i], 0, 0, 0);
    }
#pragma unroll
    for (int i = 0; i < 4; ++i)
#pragma unroll
      for (int j = 0; j < 8; ++j)
        acc[i][j] = __builtin_amdgcn_mfma_f32_16x16x32_bf16(af[i], bfr[j], acc[i][j], 0, 0, 0);
    // ---- s = 1 ----
#pragma unroll
    for (int i = 0; i < 4; ++i) af[i]  = *(const bf16x8*)&cA[rpA[i] + ck1];
#pragma unroll
    for (int j = 0; j < 8; ++j) bfr[j] = *(const bf16x8*)&cB[rpB[j] + ck1];
    if constexpr (EPI == 1){
      const bf16x8 cbs = *(const bf16x8*)&cl[(t << 6) + 32 + q*8];
#pragma unroll
      for (int i = 0; i < 4; ++i)
        accR[i] = __builtin_amdgcn_mfma_f32_16x16x32_bf16(af[i], cbs, accR[i], 0, 0, 0);
    }
#pragma unroll
    for (int i = 0; i < 4; ++i)
#pragma unroll
      for (int j = 0; j < 8; ++j)
        acc[i][j] = __builtin_amdgcn_mfma_f32_16x16x32_bf16(af[i], bfr[j], acc[i][j], 0, 0, 0);
    __syncthreads();
  }

  const int rbase = bx*256 + wr*64;
  const int cbase = by*256 + wc*128;
#pragma unroll
  for (int j = 0; j < 8; ++j){
    const int gc = cbase + j*16 + l15;
    float scale = 0.f, bias = 0.f;
    if (EPI == 0 || EPI == 2){
      scale = pg[gc] * rsqrtf(pv[gc] + 1e-5f);
      bias  = pb[gc] - pm[gc]*scale;
    }
#pragma unroll
    for (int i = 0; i < 4; ++i){
      const int gr0 = rbase + i*16 + q*4;
      if (EPI == 0){
        const float4 cv = *(const float4*)&cinv[(size_t)bb*NP + gr0];
        ushort4 pk;
        pk.x = f2bf(fmaxf(acc[i][j][0]*scale + bias, 0.f) * cv.x);
        pk.y = f2bf(fmaxf(acc[i][j][1]*scale + bias, 0.f) * cv.y);
        pk.z = f2bf(fmaxf(acc[i][j][2]*scale + bias, 0.f) * cv.z);
        pk.w = f2bf(fmaxf(acc[i][j][3]*scale + bias, 0.f) * cv.w);
        *(ushort4*)&((u16*)out0)[(size_t)bb*ostr + (size_t)gc*ldo + gr0] = pk;
      } else if (EPI == 1){
#pragma unroll
        for (int r = 0; r < 4; ++r){
          const int gr = gr0 + r;
          const size_t idx = (size_t)bb*ostr + (size_t)gr*ldo + gc;
          const float rsv = 1.f / (1e-9f + accR[i][r]);
          const float x1v = bf2f(x1h[idx]) + bf2f(x1l[idx]);
          ((u16*)out0)[idx] = f2bf(x1v - acc[i][j][r]*rsv);
        }
      } else {
        float4 o4;
#pragma unroll
        for (int r = 0; r < 4; ++r){
          const int gr = gr0 + r;
          const size_t xidx = (size_t)bb*((size_t)NP*CH) + (size_t)gr*CH + gc;
          const float x2  = fmaxf(acc[i][j][r]*scale + bias, 0.f);
          const float x1v = bf2f(x1h[xidx]) + bf2f(x1l[xidx]);
          (&o4.x)[r] = x1v + x2;
        }
        *(float4*)&((float*)out0)[(size_t)bb*ostr + (size_t)gc*ldo + gr0] = o4;
      }
    }
  }
}

// ---------------------------------------------------------------------------
// gemm_split_big: conv1 (split-precision) 256x256 tile, BK=32, 2-phase dbuf.
// ---------------------------------------------------------------------------
__global__ __launch_bounds__(512, 2) void gemm_split_big(
    const u16* __restrict__ Ah, const u16* __restrict__ Al,
    const u16* __restrict__ Bh, const u16* __restrict__ Bl,
    int lda, int ldb, long astr, long bstr, int K,
    u16* __restrict__ outH, u16* __restrict__ outL,
    long ostr, int ldo,
    const float* __restrict__ pg, const float* __restrict__ pb,
    const float* __restrict__ pm, const float* __restrict__ pv)
{
  __shared__ __align__(16) u16 sAh[2][8192], sAl[2][8192];   // 256 x 32
  __shared__ __align__(16) u16 sBh[2][8192], sBl[2][8192];

  const int tid  = threadIdx.x;
  const int lane = tid & 63;
  const int wave = tid >> 6;
  const int wr = wave >> 1, wc = wave & 1;
  const int l15 = lane & 15, q = lane >> 4;
  const int id = blockIdx.x;
  const int bb = id & 7;
  const int rest = id >> 3;
  const int by = rest & 3;
  const int bx = rest >> 2;

  const u16* Abh = Ah + (size_t)bb*astr + (size_t)bx*256*lda;
  const u16* Abl = Al + (size_t)bb*astr + (size_t)bx*256*lda;
  const u16* Bbh = Bh + (size_t)bb*bstr + (size_t)by*256*ldb;
  const u16* Bbl = Bl + (size_t)bb*bstr + (size_t)by*256*ldb;

  const int sr = tid >> 2;                              // 0..127
  const int sg = (((tid & 3) ^ ((sr >> 1) & 3)) << 3);  // pre-swizzled chunk

  auto stage = [&](int kt, int bsel){
    gl2lds16(Abh + (size_t)sr*lda        + kt + sg, &sAh[bsel][tid*8]);
    gl2lds16(Abh + (size_t)(sr+128)*lda  + kt + sg, &sAh[bsel][4096 + tid*8]);
    gl2lds16(Abl + (size_t)sr*lda        + kt + sg, &sAl[bsel][tid*8]);
    gl2lds16(Abl + (size_t)(sr+128)*lda  + kt + sg, &sAl[bsel][4096 + tid*8]);
    gl2lds16(Bbh + (size_t)sr*ldb        + kt + sg, &sBh[bsel][tid*8]);
    gl2lds16(Bbh + (size_t)(sr+128)*ldb  + kt + sg, &sBh[bsel][4096 + tid*8]);
    gl2lds16(Bbl + (size_t)sr*ldb        + kt + sg, &sBl[bsel][tid*8]);
    gl2lds16(Bbl + (size_t)(sr+128)*ldb  + kt + sg, &sBl[bsel][4096 + tid*8]);
  };

  int offA[4], offB[8];
#pragma unroll
  for (int i = 0; i < 4; ++i){
    const int ra = wr*64 + i*16 + l15;
    offA[i] = ra*32 + ((q ^ ((ra >> 1) & 3)) << 3);
  }
#pragma unroll
  for (int j = 0; j < 8; ++j){
    const int rb = wc*128 + j*16 + l15;
    offB[j] = rb*32 + ((q ^ ((rb >> 1) & 3)) << 3);
  }

  f32x4 acc[4][8] = {};

  const int NT = K >> 5;
  stage(0, 0);
  __syncthreads();

  for (int t = 0; t < NT; ++t){
    if (t + 1 < NT) stage((t + 1) << 5, (t + 1) & 1);
    const int cur = t & 1;
    bf16x8 ah[4], al2[4];
#pragma unroll
    for (int i = 0; i < 4; ++i){
      ah[i]  = *(const bf16x8*)&sAh[cur][offA[i]];
      al2[i] = *(const bf16x8*)&sAl[cur][offA[i]];
    }
#pragma unroll
    for (int jh = 0; jh < 2; ++jh){
      bf16x8 bh[4], bl[4];
#pragma unroll
      for (int j = 0; j < 4; ++j){
        bh[j] = *(const bf16x8*)&sBh[cur][offB[jh*4 + j]];
        bl[j] = *(const bf16x8*)&sBl[cur][offB[jh*4 + j]];
      }
#pragma unroll
      for (int i = 0; i < 4; ++i)
#pragma unroll
        for (int j = 0; j < 4; ++j){
          acc[i][jh*4+j] = __builtin_amdgcn_mfma_f32_16x16x32_bf16(ah[i],  bh[j], acc[i][jh*4+j], 0, 0, 0);
          acc[i][jh*4+j] = __builtin_amdgcn_mfma_f32_16x16x32_bf16(ah[i],  bl[j], acc[i][jh*4+j], 0, 0, 0);
          acc[i][jh*4+j] = __builtin_amdgcn_mfma_f32_16x16x32_bf16(al2[i], bh[j], acc[i][jh*4+j], 0, 0, 0);
        }
    }
    __syncthreads();
  }

  const int rbase = bx*256 + wr*64;
  const int cbase = by*256 + wc*128;
#pragma unroll
  for (int j = 0; j < 8; ++j){
    const int gc = cbase + j*16 + l15;
    const float scale = pg[gc] * rsqrtf(pv[gc] + 1e-5f);
    const float bias  = pb[gc] - pm[gc]*scale;
#pragma unroll
    for (int i = 0; i < 4; ++i){
      const int gr0 = rbase + i*16 + q*4;
#pragma unroll
      for (int r = 0; r < 4; ++r){
        const size_t idx = (size_t)bb*ostr + (size_t)(gr0 + r)*ldo + gc;
        const float y = fmaxf(acc[i][j][r]*scale + bias, 0.f);
        const u16 h = f2bf(y);
        outH[idx] = h;
        outL[idx] = f2bf(y - bf2f(h));
      }
    }
  }
}

// ---------------------------------------------------------------------------
// Split-bf16 GEMM (128x128): conv34 (EPI 0) + scores (EPI 1). r3-verified.
// ---------------------------------------------------------------------------
template<int EPI>
__global__ __launch_bounds__(256, 4) void gemm_split3(
    const u16* __restrict__ Ah, const u16* __restrict__ Al,
    const u16* __restrict__ Bh, const u16* __restrict__ Bl,
    int lda, int ldb, long astr, long bstr, int K,
    u16* __restrict__ outH, u16* __restrict__ outL,
    long ostr, int ldo,
    const float* __restrict__ pg, const float* __restrict__ pb,
    const float* __restrict__ pm, const float* __restrict__ pv,
    float* __restrict__ colsum, int gymask, int gyshift)
{
  __shared__ __align__(16) u16 sAh[4096], sAl[4096], sBh[4096], sBl[4096];
  const int tid  = threadIdx.x;
  const int lane = tid & 63, wave = tid >> 6;
  const int wr = wave & 1, wc = wave >> 1;
  const int l15 = lane & 15, q = lane >> 4;
  const int id = blockIdx.x;
  const int bb = id & 7;
  const int rest = id >> 3;
  const int by = rest & gymask;
  const int bx = rest >> gyshift;
  const u16* Abh = Ah + (size_t)bb*astr + (size_t)bx*128*lda;
  const u16* Abl = Al + (size_t)bb*astr + (size_t)bx*128*lda;
  const u16* Bbh = Bh + (size_t)bb*bstr + (size_t)by*128*ldb;
  const u16* Bbl = Bl + (size_t)bb*bstr + (size_t)by*128*ldb;

  f32x4 acc[4][4] = {};

  const int r0 = tid >> 2, r1 = r0 + 64;
  const int cs = (((tid & 3) ^ ((r0 >> 1) & 3)) << 3);

  int offA[4], offB[4];
#pragma unroll
  for (int i = 0; i < 4; ++i){
    const int ra = wr*64 + i*16 + l15;
    offA[i] = ra*32 + ((q ^ ((ra >> 1) & 3)) << 3);
    const int rb = wc*64 + i*16 + l15;
    offB[i] = rb*32 + ((q ^ ((rb >> 1) & 3)) << 3);
  }

  for (int kt = 0; kt < K; kt += 32){
    gl2lds16(Abh + (size_t)r0*lda + kt + cs, &sAh[tid*8]);
    gl2lds16(Abh + (size_t)r1*lda + kt + cs, &sAh[2048 + tid*8]);
    gl2lds16(Abl + (size_t)r0*lda + kt + cs, &sAl[tid*8]);
    gl2lds16(Abl + (size_t)r1*lda + kt + cs, &sAl[2048 + tid*8]);
    gl2lds16(Bbh + (size_t)r0*ldb + kt + cs, &sBh[tid*8]);
    gl2lds16(Bbh + (size_t)r1*ldb + kt + cs, &sBh[2048 + tid*8]);
    gl2lds16(Bbl + (size_t)r0*ldb + kt + cs, &sBl[tid*8]);
    gl2lds16(Bbl + (size_t)r1*ldb + kt + cs, &sBl[2048 + tid*8]);
    __syncthreads();
    bf16x8 ah[4], al[4], bh2[4], bl2[4];
#pragma unroll
    for (int i = 0; i < 4; ++i){
      ah[i] = *(const bf16x8*)&sAh[offA[i]];
      al[i] = *(const bf16x8*)&sAl[offA[i]];
    }
#pragma unroll
    for (int j = 0; j < 4; ++j){
      bh2[j] = *(const bf16x8*)&sBh[offB[j]];
      bl2[j] = *(const bf16x8*)&sBl[offB[j]];
    }
#pragma unroll
    for (int i = 0; i < 4; ++i)
#pragma unroll
      for (int j = 0; j < 4; ++j){
        acc[i][j] = __builtin_amdgcn_mfma_f32_16x16x32_bf16(ah[i], bh2[j], acc[i][j], 0, 0, 0);
        acc[i][j] = __builtin_amdgcn_mfma_f32_16x16x32_bf16(ah[i], bl2[j], acc[i][j], 0, 0, 0);
        acc[i][j] = __builtin_amdgcn_mfma_f32_16x16x32_bf16(al[i], bh2[j], acc[i][j], 0, 0, 0);
      }
    __syncthreads();
  }

  const int rbase = bx*128 + wr*64;
  const int cbase = by*128 + wc*64;

  if constexpr (EPI == 1){
    __shared__ float colpart[128];
    if (tid < 128) colpart[tid] = 0.f;
    __syncthreads();
#pragma unroll
    for (int j = 0; j < 4; ++j){
      const int gc = cbase + j*16 + l15;
      float lsum = 0.f;
#pragma unroll
      for (int i = 0; i < 4; ++i){
        const int gr0 = rbase + i*16 + q*4;
#pragma unroll
        for (int r = 0; r < 4; ++r){
          const float e = __expf(fminf(acc[i][j][r], 85.f));  // scores >= 0
          outH[(size_t)bb*ostr + (size_t)(gr0 + r)*ldo + gc] = f2bf(e);
          lsum += e;
        }
      }
      atomicAdd(&colpart[wc*64 + j*16 + l15], lsum);
    }
    __syncthreads();
    if (tid < 128) atomicAdd(&colsum[(size_t)bb*NP + (size_t)by*128 + tid], colpart[tid]);
  } else {
#pragma unroll
    for (int j = 0; j < 4; ++j){
      const int gc = cbase + j*16 + l15;
      const float scale = pg[gc] * rsqrtf(pv[gc] + 1e-5f);
      const float bias  = pb[gc] - pm[gc]*scale;
#pragma unroll
      for (int i = 0; i < 4; ++i){
        const int gr0 = rbase + i*16 + q*4;
#pragma unroll
        for (int r = 0; r < 4; ++r){
          const size_t idx = (size_t)bb*ostr + (size_t)(gr0 + r)*ldo + gc;
          const float y = fmaxf(acc[i][j][r]*scale + bias, 0.f);
          const u16 h = f2bf(y);
          outH[idx] = h;
          outL[idx] = f2bf(y - bf2f(h));
        }
      }
    }
  }
}

// colinv = 1/colsum (fp32 + bf16 copies)
__global__ __launch_bounds__(256) void colinv_k(const float* __restrict__ cs,
                                                float* __restrict__ ci,
                                                u16* __restrict__ cib, int n){
  const int i = blockIdx.x*blockDim.x + threadIdx.x;
  if (i < n){
    const float v = 1.0f / cs[i];
    ci[i]  = v;
    cib[i] = f2bf(v);
  }
}

// ---------------------------------------------------------------------------
extern "C" void kernel_launch(void* const* d_in, const int* in_sizes, int n_in,
                              void* d_out, int out_size, void* d_ws, size_t ws_size,
                              hipStream_t stream){
  const float* x = (const float*)d_in[0];
  const float *W[5], *g[5], *bt[5], *mu[5], *vr[5];
  for (int i = 0; i < 5; ++i){
    W[i]  = (const float*)d_in[1 + 5*i + 0];
    g[i]  = (const float*)d_in[1 + 5*i + 1];
    bt[i] = (const float*)d_in[1 + 5*i + 2];
    mu[i] = (const float*)d_in[1 + 5*i + 3];
    vr[i] = (const float*)d_in[1 + 5*i + 4];
  }

  char* wp = (char*)d_ws;
  size_t off = 0;
  auto take = [&](size_t bytes) -> void* {
    void* p = wp + off;
    off = (off + bytes + 255) & ~(size_t)255;
    return p;
  };
  u16*   xh   = (u16*)take(33554432);   // x^T hi [b][n][c]; reused as v' [b][c][n]
  u16*   xl   = (u16*)take(33554432);   // x^T lo;           reused as t [b][m][c]
  u16*   x1h  = (u16*)take(33554432);
  u16*   x1l  = (u16*)take(33554432);
  u16*   qkh  = (u16*)take(8388608);    // [b][n][256]: cols 0-127=q, 128-255=k
  u16*   qkl  = (u16*)take(8388608);
  float* csum = (float*)take(65536);    // colsum [b][n]
  float* cinv = (float*)take(65536);    // fp32 1/colsum
  u16*   cibf = (u16*)take(32768);      // bf16 1/colsum
  u16*   w1h  = (u16*)take(2097152);
  u16*   w1l  = (u16*)take(2097152);
  u16*   w2h  = (u16*)take(2097152);
  u16*   w34h = (u16*)take(524288);     // [256][1024] stacked W3;W4
  u16*   w34l = (u16*)take(524288);
  u16*   w5h  = (u16*)take(2097152);
  float* p34  = (float*)take(4096);     // g34|b34|m34|v34

  if (ws_size < off){
    ws_marker<<<1, 1, 0, stream>>>((float*)d_out, (float)(ws_size >> 20));
    return;
  }

  u16* vh   = xh;            // x dead after conv1
  u16* tt   = xl;
  u16* expS = (u16*)d_out;   // 64 MiB bf16 = d_out exactly; overwritten by conv5

  prep_all<<<dim3(256, 7), 256, 0, stream>>>(
      W[0], W[1], W[2], W[3], W[4],
      w1h, w1l, w2h, w34h, w34l, w5h,
      g[2], bt[2], mu[2], vr[2], g[3], bt[3], mu[3], vr[3],
      p34, csum);

  transpose_split<<<dim3(32,16,8), 256, 0, stream>>>(x, xh, xl);

  // conv1: x1 = cbr(x, W1)  (split precision)   256^2 tiles
  gemm_split_big<<<dim3(256), 512, 0, stream>>>(
      xh, xl, w1h, w1l, CH, CH, (long)NP*CH, 0, CH,
      x1h, x1l, (long)NP*CH, CH, g[0], bt[0], mu[0], vr[0]);

  // conv3+conv4 fused: qk[b][n][256]             grid 16x2x8
  gemm_split3<0><<<dim3(256), 256, 0, stream>>>(
      x1h, x1l, w34h, w34l, CH, CH, (long)NP*CH, 0, CH,
      qkh, qkl, (long)NP*256, 256, p34, p34+256, p34+512, p34+768, nullptr, 1, 1);

  // scores: expS[b][m][n] = exp(k_m . q_n) bf16 + column sums   grid 16x16x8
  gemm_split3<1><<<dim3(2048), 256, 0, stream>>>(
      qkh + 128, qkl + 128, qkh, qkl, 256, 256, (long)NP*256, (long)NP*256, CQ,
      expS, nullptr, (long)NP*NP, NP,
      nullptr, nullptr, nullptr, nullptr, csum, 15, 4);

  colinv_k<<<dim3(64), 256, 0, stream>>>(csum, cinv, cibf, 8*NP);

  // conv2: v' = cbr(x1, W2) * colinv[n]  -> vh [b][c][n]        grid 8x4x8
  gemm_2ph<0><<<dim3(256), 512, 0, stream>>>(
      x1h, w2h, CH, CH, (long)NP*CH, 0, CH,
      vh, (long)CH*NP, NP, g[1], bt[1], mu[1], vr[1],
      nullptr, nullptr, cinv, nullptr);

  // attn: acc = expS . v'; rowsum via colinv-MFMA; t = x1 - acc/rowsum
  gemm_2ph<1><<<dim3(256), 512, 0, stream>>>(
      expS, vh, NP, NP, (long)NP*NP, (long)CH*NP, NP,
      tt, (long)NP*CH, CH, nullptr, nullptr, nullptr, nullptr,
      x1h, x1l, nullptr, cibf);

  // conv5 + residual -> d_out fp32 [b][c][n]
  gemm_2ph<2><<<dim3(256), 512, 0, stream>>>(
      tt, w5h, CH, CH, (long)NP*CH, 0, CH,
      d_out, (long)CH*NP, NP, g[4], bt[4], mu[4], vr[4],
      x1h, x1l, nullptr, nullptr);
}